// Round 7
// baseline (388.557 us; speedup 1.0000x reference)
//
#include <hip/hip_runtime.h>
#include <hip/hip_bf16.h>
#include <hip/hip_fp16.h>

typedef unsigned short u16;
typedef unsigned int u32;
typedef __attribute__((ext_vector_type(8))) _Float16 f16x8;
typedef __attribute__((ext_vector_type(4))) float f32x4;

#define Q_N  6400
#define S_N  7979
#define BEV  80

__device__ __forceinline__ float f16tof(u16 u) {
    __half h; *(u16*)&h = u; return __half2float(h);
}
__device__ __forceinline__ u16 ftof16(float f) {
    __half h = __float2half(f); return *(u16*)&h;
}

// =================== fused-head GEMM body (BM=64, BN=128, BK=32) ===================
// R4-proven: single-buffer, 2 barriers/K-step. C(M,N) = A(M,K) @ W(K,N);
// WT (N,K) f16 pre-transposed. SM4: owt softmax (cols>=64 of N=128).
template <int AIN, int RELU, int OUTMODE, int SM4, int SM32>
__device__ __forceinline__ void gemm_body(
    const void* __restrict__ A, const u16* __restrict__ WT,
    const float* __restrict__ bias, const float* __restrict__ bias2,
    void* __restrict__ Cout, int M, int N, int K, int bx, int by,
    u16* Ah, u16* Wh)
{
    const int tid  = threadIdx.x;
    const int lane = tid & 63;
    const int wave = tid >> 6;
    const int wm = (wave >> 1) * 32, wn = (wave & 1) * 64;
    const int m0 = by * 64, n0 = bx * 128;
    const int arow = tid >> 2, ak = (tid & 3) * 8;
    const int wrow = tid >> 1, wk = (tid & 1) * 16;
    const int fr = lane & 15, g = lane >> 4;

    f32x4 acc[8];
    #pragma unroll
    for (int i = 0; i < 8; ++i) acc[i] = (f32x4)(0.f);

    for (int k0 = 0; k0 < K; k0 += 32) {
        {
            const bool okr = (m0 + arow) < M;
            u16* dh = &Ah[arow * 40 + ak];
            if (AIN == 0) {
                const float* ap = (const float*)A + (size_t)(m0 + arow) * K + k0 + ak;
                float4 v0 = okr ? *(const float4*)(ap)     : make_float4(0.f, 0.f, 0.f, 0.f);
                float4 v1 = okr ? *(const float4*)(ap + 4) : make_float4(0.f, 0.f, 0.f, 0.f);
                u16 hb[8];
                hb[0] = ftof16(v0.x); hb[1] = ftof16(v0.y);
                hb[2] = ftof16(v0.z); hb[3] = ftof16(v0.w);
                hb[4] = ftof16(v1.x); hb[5] = ftof16(v1.y);
                hb[6] = ftof16(v1.z); hb[7] = ftof16(v1.w);
                *(ushort4*)(dh)     = *(ushort4*)&hb[0];
                *(ushort4*)(dh + 4) = *(ushort4*)&hb[4];
            } else {
                const u16* ap = (const u16*)A + (size_t)(m0 + arow) * K + k0 + ak;
                uint4 u = okr ? *(const uint4*)ap : make_uint4(0, 0, 0, 0);
                *(uint4*)dh = u;
            }
        }
        {
            const size_t wo = (size_t)(n0 + wrow) * K + k0 + wk;
            *(uint4*)&Wh[wrow * 40 + wk]     = *(const uint4*)(WT + wo);
            *(uint4*)&Wh[wrow * 40 + wk + 8] = *(const uint4*)(WT + wo + 8);
        }
        __syncthreads();
        f16x8 fah[2], fwh[4];
        #pragma unroll
        for (int i = 0; i < 2; ++i)
            fah[i] = *(const f16x8*)&Ah[(wm + i * 16 + fr) * 40 + g * 8];
        #pragma unroll
        for (int j = 0; j < 4; ++j)
            fwh[j] = *(const f16x8*)&Wh[(wn + j * 16 + fr) * 40 + g * 8];
        #pragma unroll
        for (int i = 0; i < 2; ++i)
            #pragma unroll
            for (int j = 0; j < 4; ++j)
                acc[i * 4 + j] = __builtin_amdgcn_mfma_f32_16x16x32_f16(fah[i], fwh[j], acc[i * 4 + j], 0, 0, 0);
        __syncthreads();
    }
    // epilogue: C/D layout col=lane&15, row=(lane>>4)*4+reg
    const int g4r = g * 4;
    float bv[4];
    #pragma unroll
    for (int j = 0; j < 4; ++j) {
        int col = n0 + wn + j * 16 + fr;
        if (bias2) bv[j] = (col < 512) ? bias[col] : bias2[col - 512];
        else       bv[j] = bias ? bias[col] : 0.f;
    }
    const bool do_sm4  = SM4 && (wn == 64);
    #pragma unroll
    for (int i = 0; i < 2; ++i) {
        #pragma unroll
        for (int r = 0; r < 4; ++r) {
            const int row = m0 + wm + i * 16 + g4r + r;
            float v0 = acc[i * 4 + 0][r] + bv[0];
            float v1 = acc[i * 4 + 1][r] + bv[1];
            float v2 = acc[i * 4 + 2][r] + bv[2];
            float v3 = acc[i * 4 + 3][r] + bv[3];
            if (RELU) {
                v0 = fmaxf(v0, 0.f); v1 = fmaxf(v1, 0.f);
                v2 = fmaxf(v2, 0.f); v3 = fmaxf(v3, 0.f);
            }
            if (SM4 && do_sm4) {
                float m0q = fmaxf(v0, __shfl_xor(v0, 1));
                m0q = fmaxf(m0q, __shfl_xor(m0q, 2));
                float e0 = __expf(v0 - m0q);
                float s0 = e0 + __shfl_xor(e0, 1);
                s0 += __shfl_xor(s0, 2);
                v0 = e0 / s0;
                float m1q = fmaxf(v1, __shfl_xor(v1, 1));
                m1q = fmaxf(m1q, __shfl_xor(m1q, 2));
                float e1 = __expf(v1 - m1q);
                float s1 = e1 + __shfl_xor(e1, 1);
                s1 += __shfl_xor(s1, 2);
                v1 = e1 / s1;
                v2 = 0.f; v3 = 0.f;   // padding cols
            }
            if (row < M) {
                const int colb = n0 + wn + fr;
                if (OUTMODE == 1) {
                    u16* cp = (u16*)Cout + (size_t)row * N;
                    cp[colb]      = ftof16(v0);
                    cp[colb + 16] = ftof16(v1);
                    cp[colb + 32] = ftof16(v2);
                    cp[colb + 48] = ftof16(v3);
                } else {
                    float* cp = (float*)Cout + (size_t)row * N;
                    cp[colb]      = v0;
                    cp[colb + 16] = v1;
                    cp[colb + 32] = v2;
                    cp[colb + 48] = v3;
                }
            }
        }
    }
}

// fused head A: q->vcur_f16 | hist->vhist_f16 | q@Wc->owt(+sm4). 500 blocks.
__global__ __launch_bounds__(256) void fused3a_k(
    const float* __restrict__ q, const float* __restrict__ hist,
    const u16* __restrict__ Wv_t_h, const u16* __restrict__ Wc_h,
    const float* __restrict__ bc,
    u16* __restrict__ vcur, u16* __restrict__ vhist, float* __restrict__ owt)
{
    __shared__ u16 Ah[64 * 40], Wh[128 * 40];
    const int b = blockIdx.x;
    if (b < 200) {
        gemm_body<0, 0, 1, 0, 0>(q, Wv_t_h, nullptr, nullptr, vcur,
                                 6400, 256, 256, b & 1, b >> 1, Ah, Wh);
    } else if (b < 400) {
        int l = b - 200;
        gemm_body<0, 0, 1, 0, 0>(hist, Wv_t_h, nullptr, nullptr, vhist,
                                 6400, 256, 256, l & 1, l >> 1, Ah, Wh);
    } else {
        int l = b - 400;
        gemm_body<0, 0, 0, 1, 0>(q, Wc_h, bc, nullptr, owt,
                                 6400, 128, 256, 0, l, Ah, Wh);
    }
}

// =================== bilinear (f16 source, 4ch) ===================
__device__ __forceinline__ float4 bilin4h(const u16* __restrict__ v, int H, int W,
                                          float x, float y, int chb)
{
    float xf = floorf(x), yf = floorf(y);
    int x0 = (int)xf, y0 = (int)yf;
    int x1 = x0 + 1, y1 = y0 + 1;
    float fx = x - xf, fy = y - yf;
    float w00 = (1.f - fx) * (1.f - fy), w10 = fx * (1.f - fy);
    float w01 = (1.f - fx) * fy,         w11 = fx * fy;
    bool xi0 = (x0 >= 0) && (x0 < W);
    bool xi1 = (x1 >= 0) && (x1 < W);
    bool yi0 = (y0 >= 0) && (y0 < H);
    bool yi1 = (y1 >= 0) && (y1 < H);
    float4 r = make_float4(0.f, 0.f, 0.f, 0.f);
    #define CORNER(xi, yi, xx, yy, ww)                                           \
        if ((yi) && (xi)) {                                                      \
            uint2 u = *(const uint2*)(v + ((size_t)(yy) * W + (xx)) * 256 + chb);\
            float2 f0 = __half22float2(*(const __half2*)&u.x);                   \
            float2 f1 = __half22float2(*(const __half2*)&u.y);                   \
            r.x += (ww) * f0.x; r.y += (ww) * f0.y;                              \
            r.z += (ww) * f1.x; r.w += (ww) * f1.y;                              \
        }
    CORNER(xi0, yi0, x0, y0, w00)
    CORNER(xi1, yi0, x1, y0, w10)
    CORNER(xi0, yi1, x0, y1, w01)
    CORNER(xi1, yi1, x1, y1, w11)
    #undef CORNER
    return r;
}

// temporal deformable attention body (one query), smem >= 4KB
__device__ __forceinline__ void temporal_body(
    const u16* __restrict__ vcur, const u16* __restrict__ vhist,
    const float* __restrict__ ow, const float* __restrict__ Tm,
    float* __restrict__ outt, int b, char* smem)
{
    const int q = (b & 7) * 800 + (b >> 3);     // XCD-contiguous strips
    const int tid = threadIdx.x;
    const int c4 = tid & 63, rep = tid >> 6;
    const int br = rep >> 1, p = rep & 1;
    const int h = c4 >> 3;
    const int chb = h * 32 + (c4 & 7) * 4;
    const int jx = q % BEV, iy = q / BEV;
    const float refx = (jx + 0.5f) / 80.f;
    const float refy = (iy + 0.5f) / 80.f;
    const float wx = (refx - 0.5f) * 40.96f;
    const float wy = (refy - 0.5f) * 40.96f;
    float bx, by;
    const u16* v;
    if (br == 0) { v = vcur; bx = refx; by = refy; }
    else {
        float h0 = Tm[0] * wx + Tm[1] * wy + Tm[2];
        float h1 = Tm[3] * wx + Tm[4] * wy + Tm[5];
        float h2 = Tm[6] * wx + Tm[7] * wy + Tm[8];
        v = vhist;
        bx = h0 / h2 / 40.96f + 0.5f;
        by = h1 / h2 / 40.96f + 0.5f;
    }
    const float* owq = ow + (size_t)q * 128;
    int ob = h * 8 + br * 4 + p * 2;
    float lx = bx + owq[ob] * (1.f / 80.f);
    float ly = by + owq[ob + 1] * (1.f / 80.f);
    float wgt = owq[64 + h * 4 + br * 2 + p];
    float4 sv = bilin4h(v, BEV, BEV, lx * 80.f - 0.5f, ly * 80.f - 0.5f, chb);
    float4 (*s_acc)[64] = (float4 (*)[64])smem;
    s_acc[rep][c4] = make_float4(wgt * sv.x, wgt * sv.y, wgt * sv.z, wgt * sv.w);
    __syncthreads();
    if (rep == 0) {
        float4 a = s_acc[0][c4], b2 = s_acc[1][c4], c = s_acc[2][c4], d = s_acc[3][c4];
        float4 o = make_float4(a.x + b2.x + c.x + d.x, a.y + b2.y + c.y + d.y,
                               a.z + b2.z + c.z + d.z, a.w + b2.w + c.w + d.w);
        *(float4*)(outt + (size_t)q * 256 + c4 * 4) = o;
    }
}

// merged: val GEMM (blocks 0..1497) || temporal (blocks 1498..7897) — independent
__global__ __launch_bounds__(256) void valtemp_k(
    const float* __restrict__ fmaps, const u16* __restrict__ Wv_s_h,
    u16* __restrict__ val_f16,
    const u16* __restrict__ vcur, const u16* __restrict__ vhist,
    const float* __restrict__ ow, const float* __restrict__ Tm,
    float* __restrict__ outt)
{
    __shared__ __align__(16) char smem[15360];
    const int b = blockIdx.x;
    if (b < 1498) {
        u16* Ah = (u16*)smem;
        u16* Wh = (u16*)(smem + 5120);
        gemm_body<0, 0, 1, 0, 0>(fmaps, Wv_s_h, nullptr, nullptr, val_f16,
                                 47874, 256, 256, b & 1, b >> 1, Ah, Wh);
    } else {
        temporal_body(vcur, vhist, ow, Tm, outt, b - 1498, smem);
    }
}

// ====== chain GEMM (BM=32, BN=64, BK=32, deep register prefetch, 1 barrier/step) ====
// KK compile-time -> full unroll, static reg-array indices (no scratch). Prologue
// issues up to 8 W-steps + AD A-steps of global loads; steady-state loop is
// LDS-write-from-regs -> MFMA -> barrier with no global latency on critical path.
// STATS: per-row sum/sumsq of (C+res) via shfl reduce + atomics. LNA: LN(A+res)
// in A-stage from precomputed rstat; bx==0 writes normalized rows to aux.
// XCD chunk-swizzle. 4 waves = 2x2 of 16x32. Grid (N/64, M/32); nwg%8==0.
template <int AIN, int RELU, int OUTMODE, int SM32, int STATS, int LNA, int KK>
__global__ __launch_bounds__(256, 4) void cgemm_k(
    const void* __restrict__ A, const u16* __restrict__ WT,
    const float* __restrict__ bias, const float* __restrict__ bias2,
    const float* __restrict__ res, float* __restrict__ rstat,
    const float* __restrict__ lng, const float* __restrict__ lnb,
    float* __restrict__ aux,
    void* __restrict__ Cout, int M, int N)
{
    constexpr int NS = KK >> 5;
    constexpr int WD = (NS < 8) ? NS : 8;                       // W prefetch depth
    constexpr int AD = LNA ? 4 : ((NS < 8) ? NS : 8);           // A prefetch depth
    __shared__ u16 As[2][32 * 40];
    __shared__ u16 Wsh[2][64 * 40];
    const int tid  = threadIdx.x;
    const int lane = tid & 63;
    const int wave = tid >> 6;
    const int wm = (wave >> 1) * 16, wn = (wave & 1) * 32;
    const int fr = lane & 15, g = lane >> 4;
    const int nx = gridDim.x;
    const int nwg = nx * gridDim.y;
    const int o = blockIdx.y * nx + blockIdx.x;
    const int flat = (o & 7) * (nwg >> 3) + (o >> 3);   // XCD chunk swizzle (nwg%8==0)
    const int bx = flat % nx, by = flat / nx;
    const int m0 = by * 32, n0 = bx * 64;
    const int ar = tid >> 3, ak = (tid & 7) * 4;        // A stage: 32 rows x 32 k
    const int wr = tid >> 2, wk = (tid & 3) * 8;        // W stage: 64 rows x 32 k

    f32x4 acc[2] = {(f32x4)(0.f), (f32x4)(0.f)};

    const float* apf = (const float*)A + (size_t)(m0 + ar) * KK + ak;
    const u16*  aph  = (const u16*)A + (size_t)(m0 + ar) * KK + ak;
    const u16*  wp   = WT + (size_t)(n0 + wr) * KK + wk;

    const float* rp = nullptr;
    float* auxp = nullptr;
    float mean = 0.f, rstd = 0.f;
    if (LNA) {
        rp = res + (size_t)(m0 + ar) * 256 + ak;
        if (bx == 0) auxp = aux + (size_t)(m0 + ar) * 256 + ak;
        const float sm = rstat[m0 + ar];
        const float sq = rstat[Q_N + m0 + ar];
        mean = sm * (1.f / 256.f);
        rstd = rsqrtf(sq * (1.f / 256.f) - mean * mean + 1e-5f);
    }

    // ---- prologue: issue deep prefetch ----
    uint4 wR[WD];
    #pragma unroll
    for (int s = 0; s < WD; ++s) wR[s] = *(const uint4*)(wp + s * 32);
    float4 aF[(AIN == 0) ? AD : 1];
    float4 rF[(AIN == 0 && LNA) ? AD : 1];
    uint2  aH[(AIN == 1) ? AD : 1];
    #pragma unroll
    for (int s = 0; s < AD; ++s) {
        if (AIN == 0) {
            aF[s] = *(const float4*)(apf + s * 32);
            if (LNA) rF[s] = *(const float4*)(rp + s * 32);
        } else {
            aH[s] = *(const uint2*)(aph + s * 32);
        }
    }

    // stage step t from registers into LDS buf (t compile-time in unrolled loop)
    auto stageA = [&](int t, int buf) {
        if (AIN == 0) {
            float4 v = aF[t % AD];
            if (LNA) {
                float4 rr = rF[t % AD];
                const int ko = ak + t * 32;
                float4 gg = *(const float4*)(lng + ko);
                float4 bb = *(const float4*)(lnb + ko);
                v.x = (v.x + rr.x - mean) * rstd * gg.x + bb.x;
                v.y = (v.y + rr.y - mean) * rstd * gg.y + bb.y;
                v.z = (v.z + rr.z - mean) * rstd * gg.z + bb.z;
                v.w = (v.w + rr.w - mean) * rstd * gg.w + bb.w;
                if (auxp) *(float4*)(auxp + t * 32) = v;
            }
            u16 hb[4];
            hb[0] = ftof16(v.x); hb[1] = ftof16(v.y);
            hb[2] = ftof16(v.z); hb[3] = ftof16(v.w);
            *(ushort4*)&As[buf][ar * 40 + ak] = *(ushort4*)&hb[0];
        } else {
            *(uint2*)&As[buf][ar * 40 + ak] = aH[t % AD];
        }
    };

    stageA(0, 0);
    *(uint4*)&Wsh[0][wr * 40 + wk] = wR[0];
    __syncthreads();

    #pragma unroll
    for (int s = 0; s < NS; ++s) {
        // refill rolling register buffers (consumed at iter s+depth-1)
        if (s + WD < NS) wR[s % WD] = *(const uint4*)(wp + (s + WD) * 32);
        if (AIN == 0) {
            if (s + AD < NS) {
                aF[s % AD] = *(const float4*)(apf + (s + AD) * 32);
                if (LNA) rF[s % AD] = *(const float4*)(rp + (s + AD) * 32);
            }
        } else {
            if (s + AD < NS) aH[s % AD] = *(const uint2*)(aph + (s + AD) * 32);
        }
        // stage next step into the other LDS buffer (safe: it was drained at s-1's barrier)
        if (s + 1 < NS) {
            stageA(s + 1, (s + 1) & 1);
            *(uint4*)&Wsh[(s + 1) & 1][wr * 40 + wk] = wR[(s + 1) % WD];
        }
        const int b = s & 1;
        f16x8 fa  = *(const f16x8*)&As[b][(wm + fr) * 40 + g * 8];
        f16x8 fw0 = *(const f16x8*)&Wsh[b][(wn + fr) * 40 + g * 8];
        f16x8 fw1 = *(const f16x8*)&Wsh[b][(wn + 16 + fr) * 40 + g * 8];
        acc[0] = __builtin_amdgcn_mfma_f32_16x16x32_f16(fa, fw0, acc[0], 0, 0, 0);
        acc[1] = __builtin_amdgcn_mfma_f32_16x16x32_f16(fa, fw1, acc[1], 0, 0, 0);
        __syncthreads();
    }

    // ---- epilogue: C/D layout col=lane&15, row=(lane>>4)*4+reg ----
    const int c0g = n0 + wn + fr, c1g = c0g + 16;
    float bv0, bv1;
    if (bias2) {
        bv0 = (c0g < 512) ? bias[c0g] : bias2[c0g - 512];
        bv1 = (c1g < 512) ? bias[c1g] : bias2[c1g - 512];
    } else {
        bv0 = bias ? bias[c0g] : 0.f;
        bv1 = bias ? bias[c1g] : 0.f;
    }
    const bool do_sm32 = SM32 && ((n0 + wn) >= 512);
    #pragma unroll
    for (int r = 0; r < 4; ++r) {
        const int row = m0 + wm + g * 4 + r;
        float v0 = acc[0][r] + bv0;
        float v1 = acc[1][r] + bv1;
        if (RELU) { v0 = fmaxf(v0, 0.f); v1 = fmaxf(v1, 0.f); }
        if (SM32 && do_sm32) {
            float ma = fmaxf(v0, v1);
            ma = fmaxf(ma, __shfl_xor(ma, 1));
            ma = fmaxf(ma, __shfl_xor(ma, 2));
            ma = fmaxf(ma, __shfl_xor(ma, 4));
            ma = fmaxf(ma, __shfl_xor(ma, 8));
            float e0 = __expf(v0 - ma), e1 = __expf(v1 - ma);
            float sa = e0 + e1;
            sa += __shfl_xor(sa, 1);
            sa += __shfl_xor(sa, 2);
            sa += __shfl_xor(sa, 4);
            sa += __shfl_xor(sa, 8);
            float ia = 1.f / sa;
            v0 = e0 * ia; v1 = e1 * ia;
        }
        if (STATS) {
            float t0 = v0 + res[(size_t)row * 256 + c0g];
            float t1 = v1 + res[(size_t)row * 256 + c1g];
            float s1v = t0 + t1;
            float s2v = t0 * t0 + t1 * t1;
            s1v += __shfl_xor(s1v, 1); s1v += __shfl_xor(s1v, 2);
            s1v += __shfl_xor(s1v, 4); s1v += __shfl_xor(s1v, 8);
            s2v += __shfl_xor(s2v, 1); s2v += __shfl_xor(s2v, 2);
            s2v += __shfl_xor(s2v, 4); s2v += __shfl_xor(s2v, 8);
            if (fr == 0) {
                atomicAdd(&rstat[row], s1v);
                atomicAdd(&rstat[Q_N + row], s2v);
            }
        }
        if (row < M) {
            if (OUTMODE == 1) {
                u16* cp = (u16*)Cout + (size_t)row * N;
                cp[c0g] = ftof16(v0);
                cp[c1g] = ftof16(v1);
            } else {
                float* cp = (float*)Cout + (size_t)row * N;
                cp[c0g] = v0;
                cp[c1g] = v1;
            }
        }
    }
}

// =================== weight prep: tiled transpose to f16 (+ stats zeroing) =========
__global__ __launch_bounds__(256) void wprep_k(
    const float* __restrict__ w0, const float* __restrict__ w1, const float* __restrict__ w2,
    const float* __restrict__ w3, const float* __restrict__ w4, const float* __restrict__ w5,
    const float* __restrict__ w6, const float* __restrict__ w7, u16* __restrict__ base,
    const float* __restrict__ Woff_t, const float* __restrict__ Ww_t,
    const float* __restrict__ boff_t, const float* __restrict__ bw_t,
    float* __restrict__ bc, float* __restrict__ st)
{
    const int b = blockIdx.x, tid = threadIdx.x;
    if (b >= 185) {                 // blocks 185..284: zero st1|st2 (25600 f32)
        st[(b - 185) * 256 + tid] = 0.f;
        return;
    }
    if (b == 184) {
        if (tid < 128) bc[tid] = (tid < 64) ? boff_t[tid] : (tid < 96 ? bw_t[tid - 64] : 0.f);
        return;
    }
    const int cum[10]  = {0, 16, 32, 48, 80, 96, 112, 144, 176, 184};
    const int Ks[9]    = {256, 256, 256, 256, 256, 256, 256, 512, 256};
    const int Ns[9]    = {256, 256, 256, 512, 256, 256, 512, 256, 128};
    const int hoff[9]  = {0, 65536, 131072, 196608, 327680, 393216, 458752, 589824, 720896};
    int seg = 0;
    #pragma unroll
    for (int s = 1; s < 9; ++s) if (b >= cum[s]) seg = s;
    const int K = Ks[seg], N = Ns[seg];
    const int t = b - cum[seg];
    const int ntn = N / 64;
    const int k0 = (t / ntn) * 64, n0 = (t % ntn) * 64;
    __shared__ float tile[64][65];
    const int rr = tid >> 2, cc = (tid & 3) * 16;
    if (seg < 8) {
        const float* W = seg == 0 ? w0 : seg == 1 ? w1 : seg == 2 ? w2 : seg == 3 ? w3 :
                         seg == 4 ? w4 : seg == 5 ? w5 : seg == 6 ? w6 : w7;
        #pragma unroll
        for (int c = 0; c < 4; ++c) {
            float4 v = *(const float4*)(W + (size_t)(k0 + rr) * N + n0 + cc + c * 4);
            tile[rr][cc + c * 4 + 0] = v.x;
            tile[rr][cc + c * 4 + 1] = v.y;
            tile[rr][cc + c * 4 + 2] = v.z;
            tile[rr][cc + c * 4 + 3] = v.w;
        }
    } else {
        #pragma unroll
        for (int i = 0; i < 16; ++i) {
            int n = n0 + cc + i, k = k0 + rr;
            float v = (n < 64) ? Woff_t[k * 64 + n] : (n < 96 ? Ww_t[k * 32 + n - 64] : 0.f);
            tile[rr][cc + i] = v;
        }
    }
    __syncthreads();
    const int nr = tid >> 2, kc = (tid & 3) * 16;
    u16 hb[16];
    #pragma unroll
    for (int i = 0; i < 16; ++i) hb[i] = ftof16(tile[kc + i][nr]);
    u16* hp = base + hoff[seg] + (size_t)(n0 + nr) * K + k0 + kc;
    *(ushort4*)(hp + 0)  = *(ushort4*)&hb[0];
    *(ushort4*)(hp + 4)  = *(ushort4*)&hb[4];
    *(ushort4*)(hp + 8)  = *(ushort4*)&hb[8];
    *(ushort4*)(hp + 12) = *(ushort4*)&hb[12];
}

// =================== LayerNorm over 256 ===================
__global__ __launch_bounds__(256) void ln_k(
    const float* __restrict__ x, const float* __restrict__ res,
    const float* __restrict__ g, const float* __restrict__ b,
    float* __restrict__ out)
{
    const int row = blockIdx.x, t = threadIdx.x;
    const size_t idx = (size_t)row * 256 + t;
    float v = x[idx] + res[idx];
    float s = v, ss = v * v;
    #pragma unroll
    for (int o = 32; o > 0; o >>= 1) {
        s += __shfl_down(s, o);
        ss += __shfl_down(ss, o);
    }
    __shared__ float red[8];
    __shared__ float mv[2];
    const int wv = t >> 6, ln = t & 63;
    if (ln == 0) { red[wv] = s; red[4 + wv] = ss; }
    __syncthreads();
    if (t == 0) {
        float S = red[0] + red[1] + red[2] + red[3];
        float SS = red[4] + red[5] + red[6] + red[7];
        float mean = S * (1.f / 256.f);
        float var = SS * (1.f / 256.f) - mean * mean;
        mv[0] = mean;
        mv[1] = rsqrtf(var + 1e-5f);
    }
    __syncthreads();
    out[idx] = (v - mv[0]) * mv[1] * g[t] + b[t];
}

// =================== spatial deformable attention (f16 val, f16 ow) ===================
// R4-proven: 8 slots x 32 lanes, flattened (item,level) work, branchless corners.
__global__ __launch_bounds__(256) void spatial_k(
    const u16* __restrict__ val, const u16* __restrict__ ow, // stride 768 f16
    const float* __restrict__ cam, const float* __restrict__ zrefs,
    float* __restrict__ out)
{
    const int b = blockIdx.x;
    const int q = (b & 7) * 800 + (b >> 3);     // XCD-contiguous strips
    const int tid = threadIdx.x;
    const int lane = tid & 63, wave = tid >> 6;
    const int hw = lane >> 5, lh = lane & 31;
    const int slot = wave * 2 + hw;
    const int h = lh >> 2, chb = h * 32 + (lh & 3) * 8;
    __shared__ float s_un[24], s_vn[24], s_ok[24];
    __shared__ int s_list[24];
    __shared__ int s_n;
    __shared__ float s_cnt;
    __shared__ float s_ox[256], s_oy[256], s_wt[256];  // [pk=z*8+l*2+p][h]
    __shared__ float s_part[8][256];
    const int jx = q % BEV, iy = q / BEV;
    const float wx = ((jx + 0.5f) / 80.f - 0.5f) * 40.96f;
    const float wy = ((iy + 0.5f) / 80.f - 0.5f) * 40.96f;
    if (tid < 24) {
        int v = tid >> 2, zz = tid & 3;
        float zr = zrefs[zz];
        const float* P = cam + v * 12;
        float u0 = P[0] * wx + P[1] * wy + P[2] * zr + P[3];
        float u1 = P[4] * wx + P[5] * wy + P[6] * zr + P[7];
        float dd = P[8] * wx + P[9] * wy + P[10] * zr + P[11];
        float dm = fmaxf(dd, 1e-5f);
        float un = u0 / dm / 800.f;
        float vn = u1 / dm / 480.f;
        bool ok = (dd > 1e-5f) && (un >= 0.f) && (un <= 1.f) && (vn >= 0.f) && (vn <= 1.f);
        s_un[tid] = un; s_vn[tid] = vn; s_ok[tid] = ok ? 1.f : 0.f;
    }
    {
        const u16* owq = ow + (size_t)q * 768;
        #pragma unroll
        for (int rep = 0; rep < 2; ++rep) {
            int flat = tid + rep * 256;
            int hh = flat >> 6, rem = flat & 63;
            int zz = rem >> 4, ll = (rem >> 2) & 3, pp = (rem >> 1) & 1, xy = rem & 1;
            int dst = (zz * 8 + ll * 2 + pp) * 8 + hh;
            float v = f16tof(owq[flat]);
            if (xy) s_oy[dst] = v; else s_ox[dst] = v;
        }
        int hh = tid >> 5, rem = tid & 31;
        s_wt[rem * 8 + hh] = f16tof(owq[512 + tid]);
    }
    __syncthreads();
    if (tid == 0) {
        int n = 0; float c = 0.f;
        for (int vz = 0; vz < 24; ++vz) {
            if (s_ok[vz] != 0.f) { s_list[n++] = vz; c += 1.f; }
        }
        s_n = n; s_cnt = fmaxf(c, 1.f);
    }
    __syncthreads();
    const int n4 = s_n * 4;
    float a0 = 0.f, a1 = 0.f, a2 = 0.f, a3 = 0.f, a4 = 0.f, a5 = 0.f, a6 = 0.f, a7 = 0.f;
    for (int w = slot; w < n4; w += 8) {
        const int it = w >> 2, l = w & 3;
        const int vz = s_list[it];
        const int v = vz >> 2, z = vz & 3;
        const float un = s_un[vz], vn = s_vn[vz];
        const int Hl  = (l == 0) ? 60  : (l == 1) ? 30   : (l == 2) ? 15   : 8;
        const int Wl  = (l == 0) ? 100 : (l == 1) ? 50   : (l == 2) ? 25   : 13;
        const int LSo = (l == 0) ? 0   : (l == 1) ? 6000 : (l == 2) ? 7500 : 7875;
        const u16* lv = val + ((size_t)v * S_N + LSo) * 256 + chb;
        const float unl = un * Wl - 0.5f, vnl = vn * Hl - 0.5f;
        const int Ws = Wl * 256;
        #pragma unroll
        for (int p = 0; p < 2; ++p) {
            const int idx = (z * 8 + l * 2 + p) * 8 + h;
            float x = unl + s_ox[idx];
            float y = vnl + s_oy[idx];
            float wgt = s_wt[idx];
            float xf = floorf(x), yf = floorf(y);
            int x0 = (int)xf, y0 = (int)yf;
            float fx = x - xf, fy = y - yf;
            bool xi0 = (x0 >= 0) & (x0 < Wl);
            bool xi1 = (x0 >= -1) & (x0 < Wl - 1);
            bool yi0 = (y0 >= 0) & (y0 < Hl);
            bool yi1 = (y0 >= -1) & (y0 < Hl - 1);
            int xc0 = min(max(x0, 0), Wl - 1);
            int xc1 = min(max(x0 + 1, 0), Wl - 1);
            int yc0 = min(max(y0, 0), Hl - 1);
            int yc1 = min(max(y0 + 1, 0), Hl - 1);
            float m00 = (xi0 & yi0) ? wgt : 0.f;
            float m10 = (xi1 & yi0) ? wgt : 0.f;
            float m01 = (xi0 & yi1) ? wgt : 0.f;
            float m11 = (xi1 & yi1) ? wgt : 0.f;
            __half2 w00 = __float2half2_rn((1.f - fx) * (1.f - fy) * m00);
            __half2 w10 = __float2half2_rn(fx * (1.f - fy) * m10);
            __half2 w01 = __float2half2_rn((1.f - fx) * fy * m01);
            __half2 w11 = __float2half2_rn(fx * fy * m11);
            const u16* r0p = lv + (size_t)yc0 * Ws;
            const u16* r1p = lv + (size_t)yc1 * Ws;
            uint4 u00 = *(const uint4*)(r0p + (size_t)xc0 * 256);
            uint4 u10 = *(const uint4*)(r0p + (size_t)xc1 * 256);
            uint4 u01 = *(const uint4*)(r1p + (size_t)xc0 * 256);
            uint4 u11 = *(const uint4*)(r1p + (size_t)xc1 * 256);
            __half2 h0 = __float2half2_rn(0.f), h1 = h0, h2 = h0, h3 = h0;
            {
                const __half2* hp = (const __half2*)&u00;
                h0 = __hfma2(w00, hp[0], h0); h1 = __hfma2(w00, hp[1], h1);
                h2 = __hfma2(w00, hp[2], h2); h3 = __hfma2(w00, hp[3], h3);
            }
            {
                const __half2* hp = (const __half2*)&u10;
                h0 = __hfma2(w10, hp[0], h0); h1 = __hfma2(w10, hp[1], h1);
                h2 = __hfma2(w10, hp[2], h2); h3 = __hfma2(w10, hp[3], h3);
            }
            {
                const __half2* hp = (const __half2*)&u01;
                h0 = __hfma2(w01, hp[0], h0); h1 = __hfma2(w01, hp[1], h1);
                h2 = __hfma2(w01, hp[2], h2); h3 = __hfma2(w01, hp[3], h3);
            }
            {
                const __half2* hp = (const __half2*)&u11;
                h0 = __hfma2(w11, hp[0], h0); h1 = __hfma2(w11, hp[1], h1);
                h2 = __hfma2(w11, hp[2], h2); h3 = __hfma2(w11, hp[3], h3);
            }
            float2 f0 = __half22float2(h0), f1 = __half22float2(h1);
            float2 f2 = __half22float2(h2), f3 = __half22float2(h3);
            a0 += f0.x; a1 += f0.y; a2 += f1.x; a3 += f1.y;
            a4 += f2.x; a5 += f2.y; a6 += f3.x; a7 += f3.y;
        }
    }
    *(float4*)&s_part[slot][chb]     = make_float4(a0, a1, a2, a3);
    *(float4*)&s_part[slot][chb + 4] = make_float4(a4, a5, a6, a7);
    __syncthreads();
    float sum = 0.f;
    #pragma unroll
    for (int k = 0; k < 8; ++k) sum += s_part[k][tid];
    out[(size_t)q * 256 + tid] = sum / s_cnt;
}

extern "C" void kernel_launch(void* const* d_in, const int* in_sizes, int n_in,
                              void* d_out, int out_size, void* d_ws, size_t ws_size,
                              hipStream_t stream) {
    (void)in_sizes; (void)n_in; (void)out_size; (void)ws_size;
    const float* q      = (const float*)d_in[0];
    const float* hist   = (const float*)d_in[1];
    const float* fmaps  = (const float*)d_in[2];
    const float* Tm     = (const float*)d_in[3];
    const float* zrefs  = (const float*)d_in[4];
    const float* cam    = (const float*)d_in[5];
    const float* Woff_t = (const float*)d_in[7];
    const float* boff_t = (const float*)d_in[8];
    const float* Ww_t   = (const float*)d_in[9];
    const float* bw_t   = (const float*)d_in[10];
    const float* bo_t   = (const float*)d_in[12];
    const float* ln1g   = (const float*)d_in[13];
    const float* ln1b   = (const float*)d_in[14];
    const float* boff_s = (const float*)d_in[17];
    const float* bw_s   = (const float*)d_in[19];
    const float* bo_s   = (const float*)d_in[21];
    const float* ln2g   = (const float*)d_in[22];
    const float* ln2b   = (const float*)d_in[23];
    const float* b1     = (const float*)d_in[25];
    const float* b2     = (const float*)d_in[27];
    const float* ln3g   = (const float*)d_in[28];
    const float* ln3b   = (const float*)d_in[29];

    float* ws    = (float*)d_ws;
    float* r0    = ws;                   // sampled / out1 / out5            (1,638,400)
    float* r1    = ws + 1638400;         // out2                             (1,638,400)
    float* owt   = ws + 3276800;         // offt|wt fp32, 6400x128           (819,200)
    float* r4    = ws + 4096000;         // out_t / out3                     (1,638,400)
    u16*  r5u    = (u16*)(ws + 5734400); // off_s|w_s f16, 6400x768          (2,457,600 fl)
    float* of4   = ws + 8192000;         // out4                             (1,638,400)
    u16*  valbuf = (u16*)(ws + 9830400); // val_f16 12.25M u16 / hidden f16  (6,127,872 fl)
    u16*  vcur   = (u16*)(ws + 15958272);// 6400x256 f16                     (819,200 fl)
    u16*  vhist  = (u16*)(ws + 16777472);// 6400x256 f16                     (819,200 fl)
    u16*  wtab   = (u16*)(ws + 17596672);// f16 single tables, 753,664 u16
    float* st1   = ws + 17973504;        // LN1 stats: sum|sumsq (12,800)
    float* st2   = ws + 17986304;        // LN2 stats: sum|sumsq (12,800)
    float* bc    = ws + 18350336;        // 128

    u16* hidden = valbuf;  // reused after spatial
    u16* Wv_t_h = wtab + 0;
    u16* Wo_t_h = wtab + 65536;
    u16* Wv_s_h = wtab + 131072;
    u16* Comb_h = wtab + 196608;   // Woff_s|Ww_s (768,256)
    u16* Wo_s_h = wtab + 393216;
    u16* W1_h   = wtab + 458752;
    u16* W2_h   = wtab + 589824;
    u16* Wc_h   = wtab + 720896;

    dim3 blk(256);
    auto gc = [](int M, int N) { return dim3((unsigned)(N / 64), (unsigned)((M + 31) / 32)); };

    // 1) weight prep + zero LN-stat buffers
    wprep_k<<<dim3(285), blk, 0, stream>>>(
        (const float*)d_in[6], (const float*)d_in[11], (const float*)d_in[15],
        (const float*)d_in[16], (const float*)d_in[18], (const float*)d_in[20],
        (const float*)d_in[24], (const float*)d_in[26], wtab,
        Woff_t, Ww_t, boff_t, bw_t, bc, st1);
    // 2) head GEMMs for temporal branch (vcur, vhist, owt+softmax4)
    fused3a_k<<<dim3(500), blk, 0, stream>>>(
        q, hist, Wv_t_h, Wc_h, bc, vcur, vhist, owt);
    // 3) val GEMM || temporal sampling (independent) in one launch
    valtemp_k<<<dim3(7898), blk, 0, stream>>>(
        fmaps, Wv_s_h, valbuf, vcur, vhist, owt, Tm, r4);
    // 4) out1 = out_t @ Wo_t + bo_t; accumulate LN1 stats of (out1+q) -> st1
    cgemm_k<0,0,0,0,1,0,256><<<gc(6400, 256), blk, 0, stream>>>(
        r4, Wo_t_h, bo_t, nullptr, q, st1, nullptr, nullptr, nullptr,
        r0, 6400, 256);
    // 5) off_s|w_s = LN1(out1+q) @ Comb (LN in A-stage via st1; out2 -> r1)
    cgemm_k<0,0,1,1,0,1,256><<<gc(6400, 768), blk, 0, stream>>>(
        r0, Comb_h, boff_s, bw_s, q, st1, ln1g, ln1b, r1,
        r5u, 6400, 768);
    // 6) spatial sampling
    spatial_k<<<dim3(6400), blk, 0, stream>>>(valbuf, r5u, cam, zrefs, r0);
    // 7) out3 = sampled @ Wo_s + bo_s; accumulate LN2 stats of (out3+out2) -> st2
    cgemm_k<0,0,0,0,1,0,256><<<gc(6400, 256), blk, 0, stream>>>(
        r0, Wo_s_h, bo_s, nullptr, r1, st2, nullptr, nullptr, nullptr,
        r4, 6400, 256);
    // 8) hidden = relu(LN2(out3+out2) @ W1 + b1) -> f16 (LN in A-stage; out4 -> of4)
    cgemm_k<0,1,1,0,0,1,256><<<gc(6400, 512), blk, 0, stream>>>(
        r4, W1_h, b1, nullptr, r1, st2, ln2g, ln2b, of4,
        hidden, 6400, 512);
    // 9) out5 = hidden @ W2 + b2
    cgemm_k<1,0,0,0,0,0,512><<<gc(6400, 256), blk, 0, stream>>>(
        hidden, W2_h, b2, nullptr, nullptr, nullptr, nullptr, nullptr, nullptr,
        r0, 6400, 256);
    // 10) out = LN(out5 + out4)
    ln_k<<<dim3(6400), blk, 0, stream>>>(r0, of4, ln3g, ln3b, (float*)d_out);
}

// Round 8
// 307.987 us; speedup vs baseline: 1.2616x; 1.2616x over previous
//
#include <hip/hip_runtime.h>
#include <hip/hip_bf16.h>
#include <hip/hip_fp16.h>

typedef unsigned short u16;
typedef unsigned int u32;
typedef __attribute__((ext_vector_type(8))) _Float16 f16x8;
typedef __attribute__((ext_vector_type(4))) float f32x4;

#define Q_N  6400
#define S_N  7979
#define BEV  80

__device__ __forceinline__ float f16tof(u16 u) {
    __half h; *(u16*)&h = u; return __half2float(h);
}
__device__ __forceinline__ u16 ftof16(float f) {
    __half h = __float2half(f); return *(u16*)&h;
}

// =================== fused-head GEMM body (BM=64, BN=128, BK=32) ===================
// R4-proven: single-buffer, 2 barriers/K-step. C(M,N) = A(M,K) @ W(K,N);
// WT (N,K) f16 pre-transposed. SM4: owt softmax (cols>=64 of N=128).
template <int AIN, int RELU, int OUTMODE, int SM4, int SM32>
__device__ __forceinline__ void gemm_body(
    const void* __restrict__ A, const u16* __restrict__ WT,
    const float* __restrict__ bias, const float* __restrict__ bias2,
    void* __restrict__ Cout, int M, int N, int K, int bx, int by,
    u16* Ah, u16* Wh)
{
    const int tid  = threadIdx.x;
    const int lane = tid & 63;
    const int wave = tid >> 6;
    const int wm = (wave >> 1) * 32, wn = (wave & 1) * 64;
    const int m0 = by * 64, n0 = bx * 128;
    const int arow = tid >> 2, ak = (tid & 3) * 8;
    const int wrow = tid >> 1, wk = (tid & 1) * 16;
    const int fr = lane & 15, g = lane >> 4;

    f32x4 acc[8];
    #pragma unroll
    for (int i = 0; i < 8; ++i) acc[i] = (f32x4)(0.f);

    for (int k0 = 0; k0 < K; k0 += 32) {
        {
            const bool okr = (m0 + arow) < M;
            u16* dh = &Ah[arow * 40 + ak];
            if (AIN == 0) {
                const float* ap = (const float*)A + (size_t)(m0 + arow) * K + k0 + ak;
                float4 v0 = okr ? *(const float4*)(ap)     : make_float4(0.f, 0.f, 0.f, 0.f);
                float4 v1 = okr ? *(const float4*)(ap + 4) : make_float4(0.f, 0.f, 0.f, 0.f);
                u16 hb[8];
                hb[0] = ftof16(v0.x); hb[1] = ftof16(v0.y);
                hb[2] = ftof16(v0.z); hb[3] = ftof16(v0.w);
                hb[4] = ftof16(v1.x); hb[5] = ftof16(v1.y);
                hb[6] = ftof16(v1.z); hb[7] = ftof16(v1.w);
                *(ushort4*)(dh)     = *(ushort4*)&hb[0];
                *(ushort4*)(dh + 4) = *(ushort4*)&hb[4];
            } else {
                const u16* ap = (const u16*)A + (size_t)(m0 + arow) * K + k0 + ak;
                uint4 u = okr ? *(const uint4*)ap : make_uint4(0, 0, 0, 0);
                *(uint4*)dh = u;
            }
        }
        {
            const size_t wo = (size_t)(n0 + wrow) * K + k0 + wk;
            *(uint4*)&Wh[wrow * 40 + wk]     = *(const uint4*)(WT + wo);
            *(uint4*)&Wh[wrow * 40 + wk + 8] = *(const uint4*)(WT + wo + 8);
        }
        __syncthreads();
        f16x8 fah[2], fwh[4];
        #pragma unroll
        for (int i = 0; i < 2; ++i)
            fah[i] = *(const f16x8*)&Ah[(wm + i * 16 + fr) * 40 + g * 8];
        #pragma unroll
        for (int j = 0; j < 4; ++j)
            fwh[j] = *(const f16x8*)&Wh[(wn + j * 16 + fr) * 40 + g * 8];
        #pragma unroll
        for (int i = 0; i < 2; ++i)
            #pragma unroll
            for (int j = 0; j < 4; ++j)
                acc[i * 4 + j] = __builtin_amdgcn_mfma_f32_16x16x32_f16(fah[i], fwh[j], acc[i * 4 + j], 0, 0, 0);
        __syncthreads();
    }
    // epilogue: C/D layout col=lane&15, row=(lane>>4)*4+reg
    const int g4r = g * 4;
    float bv[4];
    #pragma unroll
    for (int j = 0; j < 4; ++j) {
        int col = n0 + wn + j * 16 + fr;
        if (bias2) bv[j] = (col < 512) ? bias[col] : bias2[col - 512];
        else       bv[j] = bias ? bias[col] : 0.f;
    }
    const bool do_sm4  = SM4 && (wn == 64);
    #pragma unroll
    for (int i = 0; i < 2; ++i) {
        #pragma unroll
        for (int r = 0; r < 4; ++r) {
            const int row = m0 + wm + i * 16 + g4r + r;
            float v0 = acc[i * 4 + 0][r] + bv[0];
            float v1 = acc[i * 4 + 1][r] + bv[1];
            float v2 = acc[i * 4 + 2][r] + bv[2];
            float v3 = acc[i * 4 + 3][r] + bv[3];
            if (RELU) {
                v0 = fmaxf(v0, 0.f); v1 = fmaxf(v1, 0.f);
                v2 = fmaxf(v2, 0.f); v3 = fmaxf(v3, 0.f);
            }
            if (SM4 && do_sm4) {
                float m0q = fmaxf(v0, __shfl_xor(v0, 1));
                m0q = fmaxf(m0q, __shfl_xor(m0q, 2));
                float e0 = __expf(v0 - m0q);
                float s0 = e0 + __shfl_xor(e0, 1);
                s0 += __shfl_xor(s0, 2);
                v0 = e0 / s0;
                float m1q = fmaxf(v1, __shfl_xor(v1, 1));
                m1q = fmaxf(m1q, __shfl_xor(m1q, 2));
                float e1 = __expf(v1 - m1q);
                float s1 = e1 + __shfl_xor(e1, 1);
                s1 += __shfl_xor(s1, 2);
                v1 = e1 / s1;
                v2 = 0.f; v3 = 0.f;   // padding cols
            }
            if (row < M) {
                const int colb = n0 + wn + fr;
                if (OUTMODE == 1) {
                    u16* cp = (u16*)Cout + (size_t)row * N;
                    cp[colb]      = ftof16(v0);
                    cp[colb + 16] = ftof16(v1);
                    cp[colb + 32] = ftof16(v2);
                    cp[colb + 48] = ftof16(v3);
                } else {
                    float* cp = (float*)Cout + (size_t)row * N;
                    cp[colb]      = v0;
                    cp[colb + 16] = v1;
                    cp[colb + 32] = v2;
                    cp[colb + 48] = v3;
                }
            }
        }
    }
}

// fused head: fmaps->val_f16 | q->vcur_f16 | hist->vhist_f16 | q@Wc->owt(+sm4)
__global__ __launch_bounds__(256) void fused3_k(
    const float* __restrict__ fmaps, const float* __restrict__ q, const float* __restrict__ hist,
    const u16* __restrict__ Wv_s_h, const u16* __restrict__ Wv_t_h,
    const u16* __restrict__ Wc_h, const float* __restrict__ bc,
    u16* __restrict__ val_f16, u16* __restrict__ vcur, u16* __restrict__ vhist,
    float* __restrict__ owt)
{
    __shared__ u16 Ah[64 * 40], Wh[128 * 40];
    const int b = blockIdx.x;
    if (b < 1498) {
        gemm_body<0, 0, 1, 0, 0>(fmaps, Wv_s_h, nullptr, nullptr, val_f16,
                                 47874, 256, 256, b & 1, b >> 1, Ah, Wh);
    } else if (b < 1698) {
        int l = b - 1498;
        gemm_body<0, 0, 1, 0, 0>(q, Wv_t_h, nullptr, nullptr, vcur,
                                 6400, 256, 256, l & 1, l >> 1, Ah, Wh);
    } else if (b < 1898) {
        int l = b - 1698;
        gemm_body<0, 0, 1, 0, 0>(hist, Wv_t_h, nullptr, nullptr, vhist,
                                 6400, 256, 256, l & 1, l >> 1, Ah, Wh);
    } else {
        int l = b - 1898;
        gemm_body<0, 0, 0, 1, 0>(q, Wc_h, bc, nullptr, owt,
                                 6400, 128, 256, 0, l, Ah, Wh);
    }
}

// ====== chain GEMM (BM=32, BN=64, BK=32, 2-iter lookahead, NAMED regs, 1 barrier) ====
// The load consumed at iter s was ISSUED at iter s-2 (P/Q alternating named sets,
// loop advanced by 2 so parity is compile-time; no arrays -> no scratch, rule #20).
// STATS: per-row sum/sumsq of (C+res) via shfl reduce + atomics. LNA: LN(A+res)
// in A-stage from precomputed rstat; bx==0 writes normalized rows to aux.
// XCD chunk-swizzle. 4 waves = 2x2 of 16x32. Grid (N/64, M/32); nwg%8==0.
template <int AIN, int RELU, int OUTMODE, int SM32, int STATS, int LNA>
__global__ __launch_bounds__(256, 4) void cgemm_k(
    const void* __restrict__ A, const u16* __restrict__ WT,
    const float* __restrict__ bias, const float* __restrict__ bias2,
    const float* __restrict__ res, float* __restrict__ rstat,
    const float* __restrict__ lng, const float* __restrict__ lnb,
    float* __restrict__ aux,
    void* __restrict__ Cout, int M, int N, int K)
{
    __shared__ u16 As[2][32 * 40];
    __shared__ u16 Wsh[2][64 * 40];
    const int tid  = threadIdx.x;
    const int lane = tid & 63;
    const int wave = tid >> 6;
    const int wm = (wave >> 1) * 16, wn = (wave & 1) * 32;
    const int fr = lane & 15, g = lane >> 4;
    const int nx = gridDim.x;
    const int nwg = nx * gridDim.y;
    const int o = blockIdx.y * nx + blockIdx.x;
    const int flat = (o & 7) * (nwg >> 3) + (o >> 3);   // XCD chunk swizzle (nwg%8==0)
    const int bx = flat % nx, by = flat / nx;
    const int m0 = by * 32, n0 = bx * 64;
    const int ar = tid >> 3, ak = (tid & 7) * 4;        // A stage: 32 rows x 32 k
    const int wr = tid >> 2, wk = (tid & 3) * 8;        // W stage: 64 rows x 32 k
    const int NS = K >> 5;

    f32x4 acc[2] = {(f32x4)(0.f), (f32x4)(0.f)};

    const float* apf = (const float*)A + (size_t)(m0 + ar) * K + ak;
    const u16*  aph  = (const u16*)A + (size_t)(m0 + ar) * K + ak;
    const u16*  wp   = WT + (size_t)(n0 + wr) * K + wk;

    const float* rp = nullptr;
    float* auxp = nullptr;
    float mean = 0.f, rstd = 0.f;
    if (LNA) {
        rp = res + (size_t)(m0 + ar) * 256 + ak;
        if (bx == 0) auxp = aux + (size_t)(m0 + ar) * 256 + ak;
        const float sm = rstat[m0 + ar];
        const float sq = rstat[Q_N + m0 + ar];
        mean = sm * (1.f / 256.f);
        rstd = rsqrtf(sq * (1.f / 256.f) - mean * mean + 1e-5f);
    }

    // named prefetch register sets (SSA, no arrays)
    float4 aP, aQ, rP, rQ;
    uint2  hP, hQ;
    uint4  wP, wQ;

    auto loadA = [&](int t, float4& af, float4& rf, uint2& ah) {
        if (AIN == 0) {
            af = *(const float4*)(apf + t * 32);
            if (LNA) rf = *(const float4*)(rp + t * 32);
        } else {
            ah = *(const uint2*)(aph + t * 32);
        }
    };
    auto stageA = [&](int t, int buf, float4 af, float4 rf, uint2 ah) {
        if (AIN == 0) {
            float4 v = af;
            if (LNA) {
                const int ko = ak + t * 32;
                float4 gg = *(const float4*)(lng + ko);
                float4 bb = *(const float4*)(lnb + ko);
                v.x = (v.x + rf.x - mean) * rstd * gg.x + bb.x;
                v.y = (v.y + rf.y - mean) * rstd * gg.y + bb.y;
                v.z = (v.z + rf.z - mean) * rstd * gg.z + bb.z;
                v.w = (v.w + rf.w - mean) * rstd * gg.w + bb.w;
                if (auxp) *(float4*)(auxp + t * 32) = v;
            }
            u16 hb[4];
            hb[0] = ftof16(v.x); hb[1] = ftof16(v.y);
            hb[2] = ftof16(v.z); hb[3] = ftof16(v.w);
            *(ushort4*)&As[buf][ar * 40 + ak] = *(ushort4*)&hb[0];
        } else {
            *(uint2*)&As[buf][ar * 40 + ak] = ah;
        }
    };

    // ---- prologue: stage step 0; preload steps 1 (P) and 2 (Q) ----
    {
        float4 a0, r0v; uint2 h0;
        loadA(0, a0, r0v, h0);
        uint4 w0v = *(const uint4*)wp;
        stageA(0, 0, a0, r0v, h0);
        *(uint4*)&Wsh[0][wr * 40 + wk] = w0v;
        const int t1 = (1 < NS) ? 1 : (NS - 1);
        const int t2 = (2 < NS) ? 2 : (NS - 1);
        loadA(t1, aP, rP, hP); wP = *(const uint4*)(wp + t1 * 32);
        loadA(t2, aQ, rQ, hQ); wQ = *(const uint4*)(wp + t2 * 32);
    }
    __syncthreads();

    for (int s = 0; s < NS; s += 2) {
        // ---- even iter: compute buf0 (step s); stage step s+1 from P; refill P ----
        {
            const int t = (s + 3 < NS) ? (s + 3) : (NS - 1);
            float4 aN, rN; uint2 hN; uint4 wN;
            loadA(t, aN, rN, hN); wN = *(const uint4*)(wp + t * 32);
            f16x8 fa  = *(const f16x8*)&As[0][(wm + fr) * 40 + g * 8];
            f16x8 fw0 = *(const f16x8*)&Wsh[0][(wn + fr) * 40 + g * 8];
            f16x8 fw1 = *(const f16x8*)&Wsh[0][(wn + 16 + fr) * 40 + g * 8];
            acc[0] = __builtin_amdgcn_mfma_f32_16x16x32_f16(fa, fw0, acc[0], 0, 0, 0);
            acc[1] = __builtin_amdgcn_mfma_f32_16x16x32_f16(fa, fw1, acc[1], 0, 0, 0);
            if (s + 1 < NS) {
                stageA(s + 1, 1, aP, rP, hP);
                *(uint4*)&Wsh[1][wr * 40 + wk] = wP;
            }
            aP = aN; rP = rN; hP = hN; wP = wN;
            __syncthreads();
        }
        if (s + 1 >= NS) break;
        // ---- odd iter: compute buf1 (step s+1); stage step s+2 from Q; refill Q ----
        {
            const int t = (s + 4 < NS) ? (s + 4) : (NS - 1);
            float4 aN, rN; uint2 hN; uint4 wN;
            loadA(t, aN, rN, hN); wN = *(const uint4*)(wp + t * 32);
            f16x8 fa  = *(const f16x8*)&As[1][(wm + fr) * 40 + g * 8];
            f16x8 fw0 = *(const f16x8*)&Wsh[1][(wn + fr) * 40 + g * 8];
            f16x8 fw1 = *(const f16x8*)&Wsh[1][(wn + 16 + fr) * 40 + g * 8];
            acc[0] = __builtin_amdgcn_mfma_f32_16x16x32_f16(fa, fw0, acc[0], 0, 0, 0);
            acc[1] = __builtin_amdgcn_mfma_f32_16x16x32_f16(fa, fw1, acc[1], 0, 0, 0);
            if (s + 2 < NS) {
                stageA(s + 2, 0, aQ, rQ, hQ);
                *(uint4*)&Wsh[0][wr * 40 + wk] = wQ;
            }
            aQ = aN; rQ = rN; hQ = hN; wQ = wN;
            __syncthreads();
        }
    }

    // ---- epilogue: C/D layout col=lane&15, row=(lane>>4)*4+reg ----
    const int c0g = n0 + wn + fr, c1g = c0g + 16;
    float bv0, bv1;
    if (bias2) {
        bv0 = (c0g < 512) ? bias[c0g] : bias2[c0g - 512];
        bv1 = (c1g < 512) ? bias[c1g] : bias2[c1g - 512];
    } else {
        bv0 = bias ? bias[c0g] : 0.f;
        bv1 = bias ? bias[c1g] : 0.f;
    }
    const bool do_sm32 = SM32 && ((n0 + wn) >= 512);
    #pragma unroll
    for (int r = 0; r < 4; ++r) {
        const int row = m0 + wm + g * 4 + r;
        float v0 = acc[0][r] + bv0;
        float v1 = acc[1][r] + bv1;
        if (RELU) { v0 = fmaxf(v0, 0.f); v1 = fmaxf(v1, 0.f); }
        if (SM32 && do_sm32) {
            float ma = fmaxf(v0, v1);
            ma = fmaxf(ma, __shfl_xor(ma, 1));
            ma = fmaxf(ma, __shfl_xor(ma, 2));
            ma = fmaxf(ma, __shfl_xor(ma, 4));
            ma = fmaxf(ma, __shfl_xor(ma, 8));
            float e0 = __expf(v0 - ma), e1 = __expf(v1 - ma);
            float sa = e0 + e1;
            sa += __shfl_xor(sa, 1);
            sa += __shfl_xor(sa, 2);
            sa += __shfl_xor(sa, 4);
            sa += __shfl_xor(sa, 8);
            float ia = 1.f / sa;
            v0 = e0 * ia; v1 = e1 * ia;
        }
        if (STATS) {
            float t0 = v0 + res[(size_t)row * 256 + c0g];
            float t1 = v1 + res[(size_t)row * 256 + c1g];
            float s1v = t0 + t1;
            float s2v = t0 * t0 + t1 * t1;
            s1v += __shfl_xor(s1v, 1); s1v += __shfl_xor(s1v, 2);
            s1v += __shfl_xor(s1v, 4); s1v += __shfl_xor(s1v, 8);
            s2v += __shfl_xor(s2v, 1); s2v += __shfl_xor(s2v, 2);
            s2v += __shfl_xor(s2v, 4); s2v += __shfl_xor(s2v, 8);
            if (fr == 0) {
                atomicAdd(&rstat[row], s1v);
                atomicAdd(&rstat[Q_N + row], s2v);
            }
        }
        if (row < M) {
            if (OUTMODE == 1) {
                u16* cp = (u16*)Cout + (size_t)row * N;
                cp[c0g] = ftof16(v0);
                cp[c1g] = ftof16(v1);
            } else {
                float* cp = (float*)Cout + (size_t)row * N;
                cp[c0g] = v0;
                cp[c1g] = v1;
            }
        }
    }
}

// =================== weight prep: tiled transpose to f16 (+ stats zeroing) =========
__global__ __launch_bounds__(256) void wprep_k(
    const float* __restrict__ w0, const float* __restrict__ w1, const float* __restrict__ w2,
    const float* __restrict__ w3, const float* __restrict__ w4, const float* __restrict__ w5,
    const float* __restrict__ w6, const float* __restrict__ w7, u16* __restrict__ base,
    const float* __restrict__ Woff_t, const float* __restrict__ Ww_t,
    const float* __restrict__ boff_t, const float* __restrict__ bw_t,
    float* __restrict__ bc, float* __restrict__ st)
{
    const int b = blockIdx.x, tid = threadIdx.x;
    if (b >= 185) {                 // blocks 185..284: zero st1|st2 (25600 f32)
        st[(b - 185) * 256 + tid] = 0.f;
        return;
    }
    if (b == 184) {
        if (tid < 128) bc[tid] = (tid < 64) ? boff_t[tid] : (tid < 96 ? bw_t[tid - 64] : 0.f);
        return;
    }
    const int cum[10]  = {0, 16, 32, 48, 80, 96, 112, 144, 176, 184};
    const int Ks[9]    = {256, 256, 256, 256, 256, 256, 256, 512, 256};
    const int Ns[9]    = {256, 256, 256, 512, 256, 256, 512, 256, 128};
    const int hoff[9]  = {0, 65536, 131072, 196608, 327680, 393216, 458752, 589824, 720896};
    int seg = 0;
    #pragma unroll
    for (int s = 1; s < 9; ++s) if (b >= cum[s]) seg = s;
    const int K = Ks[seg], N = Ns[seg];
    const int t = b - cum[seg];
    const int ntn = N / 64;
    const int k0 = (t / ntn) * 64, n0 = (t % ntn) * 64;
    __shared__ float tile[64][65];
    const int rr = tid >> 2, cc = (tid & 3) * 16;
    if (seg < 8) {
        const float* W = seg == 0 ? w0 : seg == 1 ? w1 : seg == 2 ? w2 : seg == 3 ? w3 :
                         seg == 4 ? w4 : seg == 5 ? w5 : seg == 6 ? w6 : w7;
        #pragma unroll
        for (int c = 0; c < 4; ++c) {
            float4 v = *(const float4*)(W + (size_t)(k0 + rr) * N + n0 + cc + c * 4);
            tile[rr][cc + c * 4 + 0] = v.x;
            tile[rr][cc + c * 4 + 1] = v.y;
            tile[rr][cc + c * 4 + 2] = v.z;
            tile[rr][cc + c * 4 + 3] = v.w;
        }
    } else {
        #pragma unroll
        for (int i = 0; i < 16; ++i) {
            int n = n0 + cc + i, k = k0 + rr;
            float v = (n < 64) ? Woff_t[k * 64 + n] : (n < 96 ? Ww_t[k * 32 + n - 64] : 0.f);
            tile[rr][cc + i] = v;
        }
    }
    __syncthreads();
    const int nr = tid >> 2, kc = (tid & 3) * 16;
    u16 hb[16];
    #pragma unroll
    for (int i = 0; i < 16; ++i) hb[i] = ftof16(tile[kc + i][nr]);
    u16* hp = base + hoff[seg] + (size_t)(n0 + nr) * K + k0 + kc;
    *(ushort4*)(hp + 0)  = *(ushort4*)&hb[0];
    *(ushort4*)(hp + 4)  = *(ushort4*)&hb[4];
    *(ushort4*)(hp + 8)  = *(ushort4*)&hb[8];
    *(ushort4*)(hp + 12) = *(ushort4*)&hb[12];
}

// =================== LayerNorm over 256 ===================
__global__ __launch_bounds__(256) void ln_k(
    const float* __restrict__ x, const float* __restrict__ res,
    const float* __restrict__ g, const float* __restrict__ b,
    float* __restrict__ out)
{
    const int row = blockIdx.x, t = threadIdx.x;
    const size_t idx = (size_t)row * 256 + t;
    float v = x[idx] + res[idx];
    float s = v, ss = v * v;
    #pragma unroll
    for (int o = 32; o > 0; o >>= 1) {
        s += __shfl_down(s, o);
        ss += __shfl_down(ss, o);
    }
    __shared__ float red[8];
    __shared__ float mv[2];
    const int wv = t >> 6, ln = t & 63;
    if (ln == 0) { red[wv] = s; red[4 + wv] = ss; }
    __syncthreads();
    if (t == 0) {
        float S = red[0] + red[1] + red[2] + red[3];
        float SS = red[4] + red[5] + red[6] + red[7];
        float mean = S * (1.f / 256.f);
        float var = SS * (1.f / 256.f) - mean * mean;
        mv[0] = mean;
        mv[1] = rsqrtf(var + 1e-5f);
    }
    __syncthreads();
    out[idx] = (v - mv[0]) * mv[1] * g[t] + b[t];
}

// =================== bilinear (f16 source, 4ch) ===================
__device__ __forceinline__ float4 bilin4h(const u16* __restrict__ v, int H, int W,
                                          float x, float y, int chb)
{
    float xf = floorf(x), yf = floorf(y);
    int x0 = (int)xf, y0 = (int)yf;
    int x1 = x0 + 1, y1 = y0 + 1;
    float fx = x - xf, fy = y - yf;
    float w00 = (1.f - fx) * (1.f - fy), w10 = fx * (1.f - fy);
    float w01 = (1.f - fx) * fy,         w11 = fx * fy;
    bool xi0 = (x0 >= 0) && (x0 < W);
    bool xi1 = (x1 >= 0) && (x1 < W);
    bool yi0 = (y0 >= 0) && (y0 < H);
    bool yi1 = (y1 >= 0) && (y1 < H);
    float4 r = make_float4(0.f, 0.f, 0.f, 0.f);
    #define CORNER(xi, yi, xx, yy, ww)                                           \
        if ((yi) && (xi)) {                                                      \
            uint2 u = *(const uint2*)(v + ((size_t)(yy) * W + (xx)) * 256 + chb);\
            float2 f0 = __half22float2(*(const __half2*)&u.x);                   \
            float2 f1 = __half22float2(*(const __half2*)&u.y);                   \
            r.x += (ww) * f0.x; r.y += (ww) * f0.y;                              \
            r.z += (ww) * f1.x; r.w += (ww) * f1.y;                              \
        }
    CORNER(xi0, yi0, x0, y0, w00)
    CORNER(xi1, yi0, x1, y0, w10)
    CORNER(xi0, yi1, x0, y1, w01)
    CORNER(xi1, yi1, x1, y1, w11)
    #undef CORNER
    return r;
}

// =================== temporal deformable attention (f16 values) ===================
__global__ __launch_bounds__(256) void temporal_k(
    const u16* __restrict__ vcur, const u16* __restrict__ vhist,
    const float* __restrict__ ow,   // stride 128: cols 0..63 off, 64..95 w
    const float* __restrict__ Tm, float* __restrict__ outt)
{
    const int b = blockIdx.x;
    const int q = (b & 7) * 800 + (b >> 3);     // XCD-contiguous strips
    const int tid = threadIdx.x;
    const int c4 = tid & 63, rep = tid >> 6;
    const int br = rep >> 1, p = rep & 1;
    const int h = c4 >> 3;
    const int chb = h * 32 + (c4 & 7) * 4;
    const int jx = q % BEV, iy = q / BEV;
    const float refx = (jx + 0.5f) / 80.f;
    const float refy = (iy + 0.5f) / 80.f;
    const float wx = (refx - 0.5f) * 40.96f;
    const float wy = (refy - 0.5f) * 40.96f;
    float bx, by;
    const u16* v;
    if (br == 0) { v = vcur; bx = refx; by = refy; }
    else {
        float h0 = Tm[0] * wx + Tm[1] * wy + Tm[2];
        float h1 = Tm[3] * wx + Tm[4] * wy + Tm[5];
        float h2 = Tm[6] * wx + Tm[7] * wy + Tm[8];
        v = vhist;
        bx = h0 / h2 / 40.96f + 0.5f;
        by = h1 / h2 / 40.96f + 0.5f;
    }
    const float* owq = ow + (size_t)q * 128;
    int ob = h * 8 + br * 4 + p * 2;
    float lx = bx + owq[ob] * (1.f / 80.f);
    float ly = by + owq[ob + 1] * (1.f / 80.f);
    float wgt = owq[64 + h * 4 + br * 2 + p];
    float4 sv = bilin4h(v, BEV, BEV, lx * 80.f - 0.5f, ly * 80.f - 0.5f, chb);
    __shared__ float4 s_acc[4][64];
    s_acc[rep][c4] = make_float4(wgt * sv.x, wgt * sv.y, wgt * sv.z, wgt * sv.w);
    __syncthreads();
    if (rep == 0) {
        float4 a = s_acc[0][c4], b2 = s_acc[1][c4], c = s_acc[2][c4], d = s_acc[3][c4];
        float4 o = make_float4(a.x + b2.x + c.x + d.x, a.y + b2.y + c.y + d.y,
                               a.z + b2.z + c.z + d.z, a.w + b2.w + c.w + d.w);
        *(float4*)(outt + (size_t)q * 256 + c4 * 4) = o;
    }
}

// =================== spatial deformable attention (f16 val, f16 ow) ===================
// R4-proven: 8 slots x 32 lanes, flattened (item,level) work, branchless corners.
__global__ __launch_bounds__(256) void spatial_k(
    const u16* __restrict__ val, const u16* __restrict__ ow, // stride 768 f16
    const float* __restrict__ cam, const float* __restrict__ zrefs,
    float* __restrict__ out)
{
    const int b = blockIdx.x;
    const int q = (b & 7) * 800 + (b >> 3);     // XCD-contiguous strips
    const int tid = threadIdx.x;
    const int lane = tid & 63, wave = tid >> 6;
    const int hw = lane >> 5, lh = lane & 31;
    const int slot = wave * 2 + hw;
    const int h = lh >> 2, chb = h * 32 + (lh & 3) * 8;
    __shared__ float s_un[24], s_vn[24], s_ok[24];
    __shared__ int s_list[24];
    __shared__ int s_n;
    __shared__ float s_cnt;
    __shared__ float s_ox[256], s_oy[256], s_wt[256];  // [pk=z*8+l*2+p][h]
    __shared__ float s_part[8][256];
    const int jx = q % BEV, iy = q / BEV;
    const float wx = ((jx + 0.5f) / 80.f - 0.5f) * 40.96f;
    const float wy = ((iy + 0.5f) / 80.f - 0.5f) * 40.96f;
    if (tid < 24) {
        int v = tid >> 2, zz = tid & 3;
        float zr = zrefs[zz];
        const float* P = cam + v * 12;
        float u0 = P[0] * wx + P[1] * wy + P[2] * zr + P[3];
        float u1 = P[4] * wx + P[5] * wy + P[6] * zr + P[7];
        float dd = P[8] * wx + P[9] * wy + P[10] * zr + P[11];
        float dm = fmaxf(dd, 1e-5f);
        float un = u0 / dm / 800.f;
        float vn = u1 / dm / 480.f;
        bool ok = (dd > 1e-5f) && (un >= 0.f) && (un <= 1.f) && (vn >= 0.f) && (vn <= 1.f);
        s_un[tid] = un; s_vn[tid] = vn; s_ok[tid] = ok ? 1.f : 0.f;
    }
    {
        const u16* owq = ow + (size_t)q * 768;
        #pragma unroll
        for (int rep = 0; rep < 2; ++rep) {
            int flat = tid + rep * 256;
            int hh = flat >> 6, rem = flat & 63;
            int zz = rem >> 4, ll = (rem >> 2) & 3, pp = (rem >> 1) & 1, xy = rem & 1;
            int dst = (zz * 8 + ll * 2 + pp) * 8 + hh;
            float v = f16tof(owq[flat]);
            if (xy) s_oy[dst] = v; else s_ox[dst] = v;
        }
        int hh = tid >> 5, rem = tid & 31;
        s_wt[rem * 8 + hh] = f16tof(owq[512 + tid]);
    }
    __syncthreads();
    if (tid == 0) {
        int n = 0; float c = 0.f;
        for (int vz = 0; vz < 24; ++vz) {
            if (s_ok[vz] != 0.f) { s_list[n++] = vz; c += 1.f; }
        }
        s_n = n; s_cnt = fmaxf(c, 1.f);
    }
    __syncthreads();
    const int n4 = s_n * 4;
    float a0 = 0.f, a1 = 0.f, a2 = 0.f, a3 = 0.f, a4 = 0.f, a5 = 0.f, a6 = 0.f, a7 = 0.f;
    for (int w = slot; w < n4; w += 8) {
        const int it = w >> 2, l = w & 3;
        const int vz = s_list[it];
        const int v = vz >> 2, z = vz & 3;
        const float un = s_un[vz], vn = s_vn[vz];
        const int Hl  = (l == 0) ? 60  : (l == 1) ? 30   : (l == 2) ? 15   : 8;
        const int Wl  = (l == 0) ? 100 : (l == 1) ? 50   : (l == 2) ? 25   : 13;
        const int LSo = (l == 0) ? 0   : (l == 1) ? 6000 : (l == 2) ? 7500 : 7875;
        const u16* lv = val + ((size_t)v * S_N + LSo) * 256 + chb;
        const float unl = un * Wl - 0.5f, vnl = vn * Hl - 0.5f;
        const int Ws = Wl * 256;
        #pragma unroll
        for (int p = 0; p < 2; ++p) {
            const int idx = (z * 8 + l * 2 + p) * 8 + h;
            float x = unl + s_ox[idx];
            float y = vnl + s_oy[idx];
            float wgt = s_wt[idx];
            float xf = floorf(x), yf = floorf(y);
            int x0 = (int)xf, y0 = (int)yf;
            float fx = x - xf, fy = y - yf;
            bool xi0 = (x0 >= 0) & (x0 < Wl);
            bool xi1 = (x0 >= -1) & (x0 < Wl - 1);
            bool yi0 = (y0 >= 0) & (y0 < Hl);
            bool yi1 = (y0 >= -1) & (y0 < Hl - 1);
            int xc0 = min(max(x0, 0), Wl - 1);
            int xc1 = min(max(x0 + 1, 0), Wl - 1);
            int yc0 = min(max(y0, 0), Hl - 1);
            int yc1 = min(max(y0 + 1, 0), Hl - 1);
            float m00 = (xi0 & yi0) ? wgt : 0.f;
            float m10 = (xi1 & yi0) ? wgt : 0.f;
            float m01 = (xi0 & yi1) ? wgt : 0.f;
            float m11 = (xi1 & yi1) ? wgt : 0.f;
            __half2 w00 = __float2half2_rn((1.f - fx) * (1.f - fy) * m00);
            __half2 w10 = __float2half2_rn(fx * (1.f - fy) * m10);
            __half2 w01 = __float2half2_rn((1.f - fx) * fy * m01);
            __half2 w11 = __float2half2_rn(fx * fy * m11);
            const u16* r0p = lv + (size_t)yc0 * Ws;
            const u16* r1p = lv + (size_t)yc1 * Ws;
            uint4 u00 = *(const uint4*)(r0p + (size_t)xc0 * 256);
            uint4 u10 = *(const uint4*)(r0p + (size_t)xc1 * 256);
            uint4 u01 = *(const uint4*)(r1p + (size_t)xc0 * 256);
            uint4 u11 = *(const uint4*)(r1p + (size_t)xc1 * 256);
            __half2 h0 = __float2half2_rn(0.f), h1 = h0, h2 = h0, h3 = h0;
            {
                const __half2* hp = (const __half2*)&u00;
                h0 = __hfma2(w00, hp[0], h0); h1 = __hfma2(w00, hp[1], h1);
                h2 = __hfma2(w00, hp[2], h2); h3 = __hfma2(w00, hp[3], h3);
            }
            {
                const __half2* hp = (const __half2*)&u10;
                h0 = __hfma2(w10, hp[0], h0); h1 = __hfma2(w10, hp[1], h1);
                h2 = __hfma2(w10, hp[2], h2); h3 = __hfma2(w10, hp[3], h3);
            }
            {
                const __half2* hp = (const __half2*)&u01;
                h0 = __hfma2(w01, hp[0], h0); h1 = __hfma2(w01, hp[1], h1);
                h2 = __hfma2(w01, hp[2], h2); h3 = __hfma2(w01, hp[3], h3);
            }
            {
                const __half2* hp = (const __half2*)&u11;
                h0 = __hfma2(w11, hp[0], h0); h1 = __hfma2(w11, hp[1], h1);
                h2 = __hfma2(w11, hp[2], h2); h3 = __hfma2(w11, hp[3], h3);
            }
            float2 f0 = __half22float2(h0), f1 = __half22float2(h1);
            float2 f2 = __half22float2(h2), f3 = __half22float2(h3);
            a0 += f0.x; a1 += f0.y; a2 += f1.x; a3 += f1.y;
            a4 += f2.x; a5 += f2.y; a6 += f3.x; a7 += f3.y;
        }
    }
    *(float4*)&s_part[slot][chb]     = make_float4(a0, a1, a2, a3);
    *(float4*)&s_part[slot][chb + 4] = make_float4(a4, a5, a6, a7);
    __syncthreads();
    float sum = 0.f;
    #pragma unroll
    for (int k = 0; k < 8; ++k) sum += s_part[k][tid];
    out[(size_t)q * 256 + tid] = sum / s_cnt;
}

extern "C" void kernel_launch(void* const* d_in, const int* in_sizes, int n_in,
                              void* d_out, int out_size, void* d_ws, size_t ws_size,
                              hipStream_t stream) {
    (void)in_sizes; (void)n_in; (void)out_size; (void)ws_size;
    const float* q      = (const float*)d_in[0];
    const float* hist   = (const float*)d_in[1];
    const float* fmaps  = (const float*)d_in[2];
    const float* Tm     = (const float*)d_in[3];
    const float* zrefs  = (const float*)d_in[4];
    const float* cam    = (const float*)d_in[5];
    const float* Woff_t = (const float*)d_in[7];
    const float* boff_t = (const float*)d_in[8];
    const float* Ww_t   = (const float*)d_in[9];
    const float* bw_t   = (const float*)d_in[10];
    const float* bo_t   = (const float*)d_in[12];
    const float* ln1g   = (const float*)d_in[13];
    const float* ln1b   = (const float*)d_in[14];
    const float* boff_s = (const float*)d_in[17];
    const float* bw_s   = (const float*)d_in[19];
    const float* bo_s   = (const float*)d_in[21];
    const float* ln2g   = (const float*)d_in[22];
    const float* ln2b   = (const float*)d_in[23];
    const float* b1     = (const float*)d_in[25];
    const float* b2     = (const float*)d_in[27];
    const float* ln3g   = (const float*)d_in[28];
    const float* ln3b   = (const float*)d_in[29];

    float* ws    = (float*)d_ws;
    float* r0    = ws;                   // sampled / out1 / out5            (1,638,400)
    float* r1    = ws + 1638400;         // out2                             (1,638,400)
    float* owt   = ws + 3276800;         // offt|wt fp32, 6400x128           (819,200)
    float* r4    = ws + 4096000;         // out_t / out3                     (1,638,400)
    u16*  r5u    = (u16*)(ws + 5734400); // off_s|w_s f16, 6400x768          (2,457,600 fl)
    float* of4   = ws + 8192000;         // out4                             (1,638,400)
    u16*  valbuf = (u16*)(ws + 9830400); // val_f16 12.25M u16 / hidden f16  (6,127,872 fl)
    u16*  vcur   = (u16*)(ws + 15958272);// 6400x256 f16                     (819,200 fl)
    u16*  vhist  = (u16*)(ws + 16777472);// 6400x256 f16                     (819,200 fl)
    u16*  wtab   = (u16*)(ws + 17596672);// f16 single tables, 753,664 u16
    float* st1   = ws + 17973504;        // LN1 stats: sum|sumsq (12,800)
    float* st2   = ws + 17986304;        // LN2 stats: sum|sumsq (12,800)
    float* bc    = ws + 18350336;        // 128

    u16* hidden = valbuf;  // reused after spatial
    u16* Wv_t_h = wtab + 0;
    u16* Wo_t_h = wtab + 65536;
    u16* Wv_s_h = wtab + 131072;
    u16* Comb_h = wtab + 196608;   // Woff_s|Ww_s (768,256)
    u16* Wo_s_h = wtab + 393216;
    u16* W1_h   = wtab + 458752;
    u16* W2_h   = wtab + 589824;
    u16* Wc_h   = wtab + 720896;

    dim3 blk(256);
    auto gc = [](int M, int N) { return dim3((unsigned)(N / 64), (unsigned)((M + 31) / 32)); };

    // 1) weight prep + zero LN-stat buffers
    wprep_k<<<dim3(285), blk, 0, stream>>>(
        (const float*)d_in[6], (const float*)d_in[11], (const float*)d_in[15],
        (const float*)d_in[16], (const float*)d_in[18], (const float*)d_in[20],
        (const float*)d_in[24], (const float*)d_in[26], wtab,
        Woff_t, Ww_t, boff_t, bw_t, bc, st1);
    // 2) fused head GEMMs (val, vcur, vhist, owt+softmax4)
    fused3_k<<<dim3(1998), blk, 0, stream>>>(
        fmaps, q, hist, Wv_s_h, Wv_t_h, Wc_h, bc,
        valbuf, vcur, vhist, owt);
    // 3) temporal sampling
    temporal_k<<<dim3(6400), blk, 0, stream>>>(vcur, vhist, owt, Tm, r4);
    // 4) out1 = out_t @ Wo_t + bo_t; accumulate LN1 stats of (out1+q) -> st1
    cgemm_k<0,0,0,0,1,0><<<gc(6400, 256), blk, 0, stream>>>(
        r4, Wo_t_h, bo_t, nullptr, q, st1, nullptr, nullptr, nullptr,
        r0, 6400, 256, 256);
    // 5) off_s|w_s = LN1(out1+q) @ Comb (LN in A-stage via st1; out2 -> r1)
    cgemm_k<0,0,1,1,0,1><<<gc(6400, 768), blk, 0, stream>>>(
        r0, Comb_h, boff_s, bw_s, q, st1, ln1g, ln1b, r1,
        r5u, 6400, 768, 256);
    // 6) spatial sampling
    spatial_k<<<dim3(6400), blk, 0, stream>>>(valbuf, r5u, cam, zrefs, r0);
    // 7) out3 = sampled @ Wo_s + bo_s; accumulate LN2 stats of (out3+out2) -> st2
    cgemm_k<0,0,0,0,1,0><<<gc(6400, 256), blk, 0, stream>>>(
        r0, Wo_s_h, bo_s, nullptr, r1, st2, nullptr, nullptr, nullptr,
        r4, 6400, 256, 256);
    // 8) hidden = relu(LN2(out3+out2) @ W1 + b1) -> f16 (LN in A-stage; out4 -> of4)
    cgemm_k<0,1,1,0,0,1><<<gc(6400, 512), blk, 0, stream>>>(
        r4, W1_h, b1, nullptr, r1, st2, ln2g, ln2b, of4,
        hidden, 6400, 512, 256);
    // 9) out5 = hidden @ W2 + b2
    cgemm_k<1,0,0,0,0,0><<<gc(6400, 256), blk, 0, stream>>>(
        hidden, W2_h, b2, nullptr, nullptr, nullptr, nullptr, nullptr, nullptr,
        r0, 6400, 256, 512);
    // 10) out = LN(out5 + out4)
    ln_k<<<dim3(6400), blk, 0, stream>>>(r0, of4, ln3g, ln3b, (float*)d_out);
}

// Round 9
// 294.555 us; speedup vs baseline: 1.3191x; 1.0456x over previous
//
#include <hip/hip_runtime.h>
#include <hip/hip_bf16.h>
#include <hip/hip_fp16.h>

typedef unsigned short u16;
typedef unsigned int u32;
typedef __attribute__((ext_vector_type(8))) _Float16 f16x8;
typedef __attribute__((ext_vector_type(4))) float f32x4;

#define Q_N  6400
#define S_N  7979
#define BEV  80

__device__ __forceinline__ float f16tof(u16 u) {
    __half h; *(u16*)&h = u; return __half2float(h);
}
__device__ __forceinline__ u16 ftof16(float f) {
    __half h = __float2half(f); return *(u16*)&h;
}

// =================== fused-head GEMM body (BM=64, BN=128, BK=32) ===================
// R4-proven: single-buffer, 2 barriers/K-step. C(M,N) = A(M,K) @ W(K,N);
// WT (N,K) f16 pre-transposed. SM4: owt softmax (cols>=64 of N=128).
template <int AIN, int RELU, int OUTMODE, int SM4, int SM32>
__device__ __forceinline__ void gemm_body(
    const void* __restrict__ A, const u16* __restrict__ WT,
    const float* __restrict__ bias, const float* __restrict__ bias2,
    void* __restrict__ Cout, int M, int N, int K, int bx, int by,
    u16* Ah, u16* Wh)
{
    const int tid  = threadIdx.x;
    const int lane = tid & 63;
    const int wave = tid >> 6;
    const int wm = (wave >> 1) * 32, wn = (wave & 1) * 64;
    const int m0 = by * 64, n0 = bx * 128;
    const int arow = tid >> 2, ak = (tid & 3) * 8;
    const int wrow = tid >> 1, wk = (tid & 1) * 16;
    const int fr = lane & 15, g = lane >> 4;

    f32x4 acc[8];
    #pragma unroll
    for (int i = 0; i < 8; ++i) acc[i] = (f32x4)(0.f);

    for (int k0 = 0; k0 < K; k0 += 32) {
        {
            const bool okr = (m0 + arow) < M;
            u16* dh = &Ah[arow * 40 + ak];
            if (AIN == 0) {
                const float* ap = (const float*)A + (size_t)(m0 + arow) * K + k0 + ak;
                float4 v0 = okr ? *(const float4*)(ap)     : make_float4(0.f, 0.f, 0.f, 0.f);
                float4 v1 = okr ? *(const float4*)(ap + 4) : make_float4(0.f, 0.f, 0.f, 0.f);
                u16 hb[8];
                hb[0] = ftof16(v0.x); hb[1] = ftof16(v0.y);
                hb[2] = ftof16(v0.z); hb[3] = ftof16(v0.w);
                hb[4] = ftof16(v1.x); hb[5] = ftof16(v1.y);
                hb[6] = ftof16(v1.z); hb[7] = ftof16(v1.w);
                *(ushort4*)(dh)     = *(ushort4*)&hb[0];
                *(ushort4*)(dh + 4) = *(ushort4*)&hb[4];
            } else {
                const u16* ap = (const u16*)A + (size_t)(m0 + arow) * K + k0 + ak;
                uint4 u = okr ? *(const uint4*)ap : make_uint4(0, 0, 0, 0);
                *(uint4*)dh = u;
            }
        }
        {
            const size_t wo = (size_t)(n0 + wrow) * K + k0 + wk;
            *(uint4*)&Wh[wrow * 40 + wk]     = *(const uint4*)(WT + wo);
            *(uint4*)&Wh[wrow * 40 + wk + 8] = *(const uint4*)(WT + wo + 8);
        }
        __syncthreads();
        f16x8 fah[2], fwh[4];
        #pragma unroll
        for (int i = 0; i < 2; ++i)
            fah[i] = *(const f16x8*)&Ah[(wm + i * 16 + fr) * 40 + g * 8];
        #pragma unroll
        for (int j = 0; j < 4; ++j)
            fwh[j] = *(const f16x8*)&Wh[(wn + j * 16 + fr) * 40 + g * 8];
        #pragma unroll
        for (int i = 0; i < 2; ++i)
            #pragma unroll
            for (int j = 0; j < 4; ++j)
                acc[i * 4 + j] = __builtin_amdgcn_mfma_f32_16x16x32_f16(fah[i], fwh[j], acc[i * 4 + j], 0, 0, 0);
        __syncthreads();
    }
    // epilogue: C/D layout col=lane&15, row=(lane>>4)*4+reg
    const int g4r = g * 4;
    float bv[4];
    #pragma unroll
    for (int j = 0; j < 4; ++j) {
        int col = n0 + wn + j * 16 + fr;
        if (bias2) bv[j] = (col < 512) ? bias[col] : bias2[col - 512];
        else       bv[j] = bias ? bias[col] : 0.f;
    }
    const bool do_sm4  = SM4 && (wn == 64);
    #pragma unroll
    for (int i = 0; i < 2; ++i) {
        #pragma unroll
        for (int r = 0; r < 4; ++r) {
            const int row = m0 + wm + i * 16 + g4r + r;
            float v0 = acc[i * 4 + 0][r] + bv[0];
            float v1 = acc[i * 4 + 1][r] + bv[1];
            float v2 = acc[i * 4 + 2][r] + bv[2];
            float v3 = acc[i * 4 + 3][r] + bv[3];
            if (RELU) {
                v0 = fmaxf(v0, 0.f); v1 = fmaxf(v1, 0.f);
                v2 = fmaxf(v2, 0.f); v3 = fmaxf(v3, 0.f);
            }
            if (SM4 && do_sm4) {
                float m0q = fmaxf(v0, __shfl_xor(v0, 1));
                m0q = fmaxf(m0q, __shfl_xor(m0q, 2));
                float e0 = __expf(v0 - m0q);
                float s0 = e0 + __shfl_xor(e0, 1);
                s0 += __shfl_xor(s0, 2);
                v0 = e0 / s0;
                float m1q = fmaxf(v1, __shfl_xor(v1, 1));
                m1q = fmaxf(m1q, __shfl_xor(m1q, 2));
                float e1 = __expf(v1 - m1q);
                float s1 = e1 + __shfl_xor(e1, 1);
                s1 += __shfl_xor(s1, 2);
                v1 = e1 / s1;
                v2 = 0.f; v3 = 0.f;   // padding cols
            }
            if (row < M) {
                const int colb = n0 + wn + fr;
                if (OUTMODE == 1) {
                    u16* cp = (u16*)Cout + (size_t)row * N;
                    cp[colb]      = ftof16(v0);
                    cp[colb + 16] = ftof16(v1);
                    cp[colb + 32] = ftof16(v2);
                    cp[colb + 48] = ftof16(v3);
                } else {
                    float* cp = (float*)Cout + (size_t)row * N;
                    cp[colb]      = v0;
                    cp[colb + 16] = v1;
                    cp[colb + 32] = v2;
                    cp[colb + 48] = v3;
                }
            }
        }
    }
}

// fused head: fmaps->val_f16 | q->vcur_f16 | hist->vhist_f16 | q@Wc->owt(+sm4)
__global__ __launch_bounds__(256) void fused3_k(
    const float* __restrict__ fmaps, const float* __restrict__ q, const float* __restrict__ hist,
    const u16* __restrict__ Wv_s_h, const u16* __restrict__ Wv_t_h,
    const u16* __restrict__ Wc_h, const float* __restrict__ bc,
    u16* __restrict__ val_f16, u16* __restrict__ vcur, u16* __restrict__ vhist,
    float* __restrict__ owt)
{
    __shared__ u16 Ah[64 * 40], Wh[128 * 40];
    const int b = blockIdx.x;
    if (b < 1498) {
        gemm_body<0, 0, 1, 0, 0>(fmaps, Wv_s_h, nullptr, nullptr, val_f16,
                                 47874, 256, 256, b & 1, b >> 1, Ah, Wh);
    } else if (b < 1698) {
        int l = b - 1498;
        gemm_body<0, 0, 1, 0, 0>(q, Wv_t_h, nullptr, nullptr, vcur,
                                 6400, 256, 256, l & 1, l >> 1, Ah, Wh);
    } else if (b < 1898) {
        int l = b - 1698;
        gemm_body<0, 0, 1, 0, 0>(hist, Wv_t_h, nullptr, nullptr, vhist,
                                 6400, 256, 256, l & 1, l >> 1, Ah, Wh);
    } else {
        int l = b - 1898;
        gemm_body<0, 0, 0, 1, 0>(q, Wc_h, bc, nullptr, owt,
                                 6400, 128, 256, 0, l, Ah, Wh);
    }
}

// =================== chain GEMM (BM=32, BN=64, BK=32, dbuf, 1 barrier/step) ==========
// R6-proven base (best: 302.8):
//  STATS: epilogue accumulates per-row sum/sumsq of (C + res) into rstat via
//         cross-fr shfl reduce + 2 atomicAdds per row-slice (for NEXT kernel's LN).
//  LNA:   A-stage applies LayerNorm to (A + res) using precomputed rstat
//         (mean/rstd per row), writes normalized rows to aux from bx==0 blocks.
// 4 waves = 2x2 of 16x32. Grid (N/64, M/32); nwg % 8 == 0 for all shapes.
template <int AIN, int RELU, int OUTMODE, int SM32, int STATS, int LNA>
__global__ __launch_bounds__(256, 4) void cgemm_k(
    const void* __restrict__ A, const u16* __restrict__ WT,
    const float* __restrict__ bias, const float* __restrict__ bias2,
    const float* __restrict__ res, float* __restrict__ rstat,
    const float* __restrict__ lng, const float* __restrict__ lnb,
    float* __restrict__ aux,
    void* __restrict__ Cout, int M, int N, int K)
{
    __shared__ u16 As[2][32 * 40];
    __shared__ u16 Wsh[2][64 * 40];
    const int tid  = threadIdx.x;
    const int lane = tid & 63;
    const int wave = tid >> 6;
    const int wm = (wave >> 1) * 16, wn = (wave & 1) * 32;
    const int fr = lane & 15, g = lane >> 4;
    const int nx = gridDim.x;
    const int nwg = nx * gridDim.y;
    const int o = blockIdx.y * nx + blockIdx.x;
    const int flat = (o & 7) * (nwg >> 3) + (o >> 3);   // XCD chunk swizzle (nwg%8==0)
    const int bx = flat % nx, by = flat / nx;
    const int m0 = by * 32, n0 = bx * 64;
    const int ar = tid >> 3, ak = (tid & 7) * 4;        // A stage: 32 rows x 32 k
    const int wr = tid >> 2, wk = (tid & 3) * 8;        // W stage: 64 rows x 32 k
    const int NS = K >> 5;

    f32x4 acc[2] = {(f32x4)(0.f), (f32x4)(0.f)};

    const float* apf = (const float*)A + (size_t)(m0 + ar) * K + ak;
    const u16*  aph  = (const u16*)A + (size_t)(m0 + ar) * K + ak;
    const u16*  wp   = WT + (size_t)(n0 + wr) * K + wk;

    const float* rp = nullptr;
    float* auxp = nullptr;
    float mean = 0.f, rstd = 0.f;
    if (LNA) {
        rp = res + (size_t)(m0 + ar) * 256 + ak;
        if (bx == 0) auxp = aux + (size_t)(m0 + ar) * 256 + ak;
        const float sm = rstat[m0 + ar];
        const float sq = rstat[Q_N + m0 + ar];
        mean = sm * (1.f / 256.f);
        rstd = rsqrtf(sq * (1.f / 256.f) - mean * mean + 1e-5f);
    }

    // stage step 0
    if (AIN == 0) {
        float4 v = *(const float4*)apf;
        if (LNA) {
            float4 rr = *(const float4*)rp;
            float4 gg = *(const float4*)(lng + ak);
            float4 bb = *(const float4*)(lnb + ak);
            v.x = (v.x + rr.x - mean) * rstd * gg.x + bb.x;
            v.y = (v.y + rr.y - mean) * rstd * gg.y + bb.y;
            v.z = (v.z + rr.z - mean) * rstd * gg.z + bb.z;
            v.w = (v.w + rr.w - mean) * rstd * gg.w + bb.w;
            if (auxp) *(float4*)auxp = v;
        }
        u16 hb[4];
        hb[0] = ftof16(v.x); hb[1] = ftof16(v.y); hb[2] = ftof16(v.z); hb[3] = ftof16(v.w);
        *(ushort4*)&As[0][ar * 40 + ak] = *(ushort4*)&hb[0];
    } else {
        *(uint2*)&As[0][ar * 40 + ak] = *(const uint2*)aph;
    }
    *(uint4*)&Wsh[0][wr * 40 + wk] = *(const uint4*)wp;
    __syncthreads();

    for (int s = 0; s < NS; ++s) {
        float4 av; float4 rv; uint2 au; uint4 wv;
        const bool pf = (s + 1) < NS;
        if (pf) {
            if (AIN == 0) {
                av = *(const float4*)(apf + (s + 1) * 32);
                if (LNA) rv = *(const float4*)(rp + (s + 1) * 32);
            } else {
                au = *(const uint2*)(aph + (s + 1) * 32);
            }
            wv = *(const uint4*)(wp + (s + 1) * 32);
        }
        const int b = s & 1;
        f16x8 fa  = *(const f16x8*)&As[b][(wm + fr) * 40 + g * 8];
        f16x8 fw0 = *(const f16x8*)&Wsh[b][(wn + fr) * 40 + g * 8];
        f16x8 fw1 = *(const f16x8*)&Wsh[b][(wn + 16 + fr) * 40 + g * 8];
        acc[0] = __builtin_amdgcn_mfma_f32_16x16x32_f16(fa, fw0, acc[0], 0, 0, 0);
        acc[1] = __builtin_amdgcn_mfma_f32_16x16x32_f16(fa, fw1, acc[1], 0, 0, 0);
        if (pf) {
            const int nb = b ^ 1;
            if (AIN == 0) {
                if (LNA) {
                    const int ko = ak + (s + 1) * 32;
                    float4 gg = *(const float4*)(lng + ko);
                    float4 bb = *(const float4*)(lnb + ko);
                    av.x = (av.x + rv.x - mean) * rstd * gg.x + bb.x;
                    av.y = (av.y + rv.y - mean) * rstd * gg.y + bb.y;
                    av.z = (av.z + rv.z - mean) * rstd * gg.z + bb.z;
                    av.w = (av.w + rv.w - mean) * rstd * gg.w + bb.w;
                    if (auxp) *(float4*)(auxp + (s + 1) * 32) = av;
                }
                u16 hb[4];
                hb[0] = ftof16(av.x); hb[1] = ftof16(av.y);
                hb[2] = ftof16(av.z); hb[3] = ftof16(av.w);
                *(ushort4*)&As[nb][ar * 40 + ak] = *(ushort4*)&hb[0];
            } else {
                *(uint2*)&As[nb][ar * 40 + ak] = au;
            }
            *(uint4*)&Wsh[nb][wr * 40 + wk] = wv;
        }
        __syncthreads();
    }

    // ---- epilogue: C/D layout col=lane&15, row=(lane>>4)*4+reg ----
    const int c0g = n0 + wn + fr, c1g = c0g + 16;
    float bv0, bv1;
    if (bias2) {
        bv0 = (c0g < 512) ? bias[c0g] : bias2[c0g - 512];
        bv1 = (c1g < 512) ? bias[c1g] : bias2[c1g - 512];
    } else {
        bv0 = bias ? bias[c0g] : 0.f;
        bv1 = bias ? bias[c1g] : 0.f;
    }
    const bool do_sm32 = SM32 && ((n0 + wn) >= 512);
    #pragma unroll
    for (int r = 0; r < 4; ++r) {
        const int row = m0 + wm + g * 4 + r;
        float v0 = acc[0][r] + bv0;
        float v1 = acc[1][r] + bv1;
        if (RELU) { v0 = fmaxf(v0, 0.f); v1 = fmaxf(v1, 0.f); }
        if (SM32 && do_sm32) {
            float ma = fmaxf(v0, v1);
            ma = fmaxf(ma, __shfl_xor(ma, 1));
            ma = fmaxf(ma, __shfl_xor(ma, 2));
            ma = fmaxf(ma, __shfl_xor(ma, 4));
            ma = fmaxf(ma, __shfl_xor(ma, 8));
            float e0 = __expf(v0 - ma), e1 = __expf(v1 - ma);
            float sa = e0 + e1;
            sa += __shfl_xor(sa, 1);
            sa += __shfl_xor(sa, 2);
            sa += __shfl_xor(sa, 4);
            sa += __shfl_xor(sa, 8);
            float ia = 1.f / sa;
            v0 = e0 * ia; v1 = e1 * ia;
        }
        if (STATS) {
            // LN stats of (out + residual) for next kernel; N == 256 here
            float t0 = v0 + res[(size_t)row * 256 + c0g];
            float t1 = v1 + res[(size_t)row * 256 + c1g];
            float s1v = t0 + t1;
            float s2v = t0 * t0 + t1 * t1;
            s1v += __shfl_xor(s1v, 1); s1v += __shfl_xor(s1v, 2);
            s1v += __shfl_xor(s1v, 4); s1v += __shfl_xor(s1v, 8);
            s2v += __shfl_xor(s2v, 1); s2v += __shfl_xor(s2v, 2);
            s2v += __shfl_xor(s2v, 4); s2v += __shfl_xor(s2v, 8);
            if (fr == 0) {
                atomicAdd(&rstat[row], s1v);
                atomicAdd(&rstat[Q_N + row], s2v);
            }
        }
        if (row < M) {
            if (OUTMODE == 1) {
                u16* cp = (u16*)Cout + (size_t)row * N;
                cp[c0g] = ftof16(v0);
                cp[c1g] = ftof16(v1);
            } else {
                float* cp = (float*)Cout + (size_t)row * N;
                cp[c0g] = v0;
                cp[c1g] = v1;
            }
        }
    }
}

// =================== weight prep: tiled transpose to f16 (+ stats zeroing) =========
__global__ __launch_bounds__(256) void wprep_k(
    const float* __restrict__ w0, const float* __restrict__ w1, const float* __restrict__ w2,
    const float* __restrict__ w3, const float* __restrict__ w4, const float* __restrict__ w5,
    const float* __restrict__ w6, const float* __restrict__ w7, u16* __restrict__ base,
    const float* __restrict__ Woff_t, const float* __restrict__ Ww_t,
    const float* __restrict__ boff_t, const float* __restrict__ bw_t,
    float* __restrict__ bc, float* __restrict__ st)
{
    const int b = blockIdx.x, tid = threadIdx.x;
    if (b >= 185) {                 // blocks 185..284: zero st1|st2 (25600 f32)
        st[(b - 185) * 256 + tid] = 0.f;
        return;
    }
    if (b == 184) {
        if (tid < 128) bc[tid] = (tid < 64) ? boff_t[tid] : (tid < 96 ? bw_t[tid - 64] : 0.f);
        return;
    }
    const int cum[10]  = {0, 16, 32, 48, 80, 96, 112, 144, 176, 184};
    const int Ks[9]    = {256, 256, 256, 256, 256, 256, 256, 512, 256};
    const int Ns[9]    = {256, 256, 256, 512, 256, 256, 512, 256, 128};
    const int hoff[9]  = {0, 65536, 131072, 196608, 327680, 393216, 458752, 589824, 720896};
    int seg = 0;
    #pragma unroll
    for (int s = 1; s < 9; ++s) if (b >= cum[s]) seg = s;
    const int K = Ks[seg], N = Ns[seg];
    const int t = b - cum[seg];
    const int ntn = N / 64;
    const int k0 = (t / ntn) * 64, n0 = (t % ntn) * 64;
    __shared__ float tile[64][65];
    const int rr = tid >> 2, cc = (tid & 3) * 16;
    if (seg < 8) {
        const float* W = seg == 0 ? w0 : seg == 1 ? w1 : seg == 2 ? w2 : seg == 3 ? w3 :
                         seg == 4 ? w4 : seg == 5 ? w5 : seg == 6 ? w6 : w7;
        #pragma unroll
        for (int c = 0; c < 4; ++c) {
            float4 v = *(const float4*)(W + (size_t)(k0 + rr) * N + n0 + cc + c * 4);
            tile[rr][cc + c * 4 + 0] = v.x;
            tile[rr][cc + c * 4 + 1] = v.y;
            tile[rr][cc + c * 4 + 2] = v.z;
            tile[rr][cc + c * 4 + 3] = v.w;
        }
    } else {
        #pragma unroll
        for (int i = 0; i < 16; ++i) {
            int n = n0 + cc + i, k = k0 + rr;
            float v = (n < 64) ? Woff_t[k * 64 + n] : (n < 96 ? Ww_t[k * 32 + n - 64] : 0.f);
            tile[rr][cc + i] = v;
        }
    }
    __syncthreads();
    const int nr = tid >> 2, kc = (tid & 3) * 16;
    u16 hb[16];
    #pragma unroll
    for (int i = 0; i < 16; ++i) hb[i] = ftof16(tile[kc + i][nr]);
    u16* hp = base + hoff[seg] + (size_t)(n0 + nr) * K + k0 + kc;
    *(ushort4*)(hp + 0)  = *(ushort4*)&hb[0];
    *(ushort4*)(hp + 4)  = *(ushort4*)&hb[4];
    *(ushort4*)(hp + 8)  = *(ushort4*)&hb[8];
    *(ushort4*)(hp + 12) = *(ushort4*)&hb[12];
}

// =================== LayerNorm over 256 ===================
__global__ __launch_bounds__(256) void ln_k(
    const float* __restrict__ x, const float* __restrict__ res,
    const float* __restrict__ g, const float* __restrict__ b,
    float* __restrict__ out)
{
    const int row = blockIdx.x, t = threadIdx.x;
    const size_t idx = (size_t)row * 256 + t;
    float v = x[idx] + res[idx];
    float s = v, ss = v * v;
    #pragma unroll
    for (int o = 32; o > 0; o >>= 1) {
        s += __shfl_down(s, o);
        ss += __shfl_down(ss, o);
    }
    __shared__ float red[8];
    __shared__ float mv[2];
    const int wv = t >> 6, ln = t & 63;
    if (ln == 0) { red[wv] = s; red[4 + wv] = ss; }
    __syncthreads();
    if (t == 0) {
        float S = red[0] + red[1] + red[2] + red[3];
        float SS = red[4] + red[5] + red[6] + red[7];
        float mean = S * (1.f / 256.f);
        float var = SS * (1.f / 256.f) - mean * mean;
        mv[0] = mean;
        mv[1] = rsqrtf(var + 1e-5f);
    }
    __syncthreads();
    out[idx] = (v - mv[0]) * mv[1] * g[t] + b[t];
}

// =================== bilinear (f16 source, 4ch) ===================
__device__ __forceinline__ float4 bilin4h(const u16* __restrict__ v, int H, int W,
                                          float x, float y, int chb)
{
    float xf = floorf(x), yf = floorf(y);
    int x0 = (int)xf, y0 = (int)yf;
    int x1 = x0 + 1, y1 = y0 + 1;
    float fx = x - xf, fy = y - yf;
    float w00 = (1.f - fx) * (1.f - fy), w10 = fx * (1.f - fy);
    float w01 = (1.f - fx) * fy,         w11 = fx * fy;
    bool xi0 = (x0 >= 0) && (x0 < W);
    bool xi1 = (x1 >= 0) && (x1 < W);
    bool yi0 = (y0 >= 0) && (y0 < H);
    bool yi1 = (y1 >= 0) && (y1 < H);
    float4 r = make_float4(0.f, 0.f, 0.f, 0.f);
    #define CORNER(xi, yi, xx, yy, ww)                                           \
        if ((yi) && (xi)) {                                                      \
            uint2 u = *(const uint2*)(v + ((size_t)(yy) * W + (xx)) * 256 + chb);\
            float2 f0 = __half22float2(*(const __half2*)&u.x);                   \
            float2 f1 = __half22float2(*(const __half2*)&u.y);                   \
            r.x += (ww) * f0.x; r.y += (ww) * f0.y;                              \
            r.z += (ww) * f1.x; r.w += (ww) * f1.y;                              \
        }
    CORNER(xi0, yi0, x0, y0, w00)
    CORNER(xi1, yi0, x1, y0, w10)
    CORNER(xi0, yi1, x0, y1, w01)
    CORNER(xi1, yi1, x1, y1, w11)
    #undef CORNER
    return r;
}

// =================== temporal deformable attention (f16 values) ===================
__global__ __launch_bounds__(256) void temporal_k(
    const u16* __restrict__ vcur, const u16* __restrict__ vhist,
    const float* __restrict__ ow,   // stride 128: cols 0..63 off, 64..95 w
    const float* __restrict__ Tm, float* __restrict__ outt)
{
    const int b = blockIdx.x;
    const int q = (b & 7) * 800 + (b >> 3);     // XCD-contiguous strips
    const int tid = threadIdx.x;
    const int c4 = tid & 63, rep = tid >> 6;
    const int br = rep >> 1, p = rep & 1;
    const int h = c4 >> 3;
    const int chb = h * 32 + (c4 & 7) * 4;
    const int jx = q % BEV, iy = q / BEV;
    const float refx = (jx + 0.5f) / 80.f;
    const float refy = (iy + 0.5f) / 80.f;
    const float wx = (refx - 0.5f) * 40.96f;
    const float wy = (refy - 0.5f) * 40.96f;
    float bx, by;
    const u16* v;
    if (br == 0) { v = vcur; bx = refx; by = refy; }
    else {
        float h0 = Tm[0] * wx + Tm[1] * wy + Tm[2];
        float h1 = Tm[3] * wx + Tm[4] * wy + Tm[5];
        float h2 = Tm[6] * wx + Tm[7] * wy + Tm[8];
        v = vhist;
        bx = h0 / h2 / 40.96f + 0.5f;
        by = h1 / h2 / 40.96f + 0.5f;
    }
    const float* owq = ow + (size_t)q * 128;
    int ob = h * 8 + br * 4 + p * 2;
    float lx = bx + owq[ob] * (1.f / 80.f);
    float ly = by + owq[ob + 1] * (1.f / 80.f);
    float wgt = owq[64 + h * 4 + br * 2 + p];
    float4 sv = bilin4h(v, BEV, BEV, lx * 80.f - 0.5f, ly * 80.f - 0.5f, chb);
    __shared__ float4 s_acc[4][64];
    s_acc[rep][c4] = make_float4(wgt * sv.x, wgt * sv.y, wgt * sv.z, wgt * sv.w);
    __syncthreads();
    if (rep == 0) {
        float4 a = s_acc[0][c4], b2 = s_acc[1][c4], c = s_acc[2][c4], d = s_acc[3][c4];
        float4 o = make_float4(a.x + b2.x + c.x + d.x, a.y + b2.y + c.y + d.y,
                               a.z + b2.z + c.z + d.z, a.w + b2.w + c.w + d.w);
        *(float4*)(outt + (size_t)q * 256 + c4 * 4) = o;
    }
}

// =================== spatial deformable attention (f16 val, f16 ow) ===================
// Two-phase: (A) all 256 threads precompute per-(point,head) corner offsets +
// masked packed-half2 weights into LDS (one tuple/thread, chunks of 4 valid
// (v,z) entries = 32 points); (B) gather loop reads precomputed tuples — no
// per-sample scalar math in the replicated inner loop. 8 slots x 32 lanes.
__global__ __launch_bounds__(256) void spatial_k(
    const u16* __restrict__ val, const u16* __restrict__ ow, // stride 768 f16
    const float* __restrict__ cam, const float* __restrict__ zrefs,
    float* __restrict__ out)
{
    const int b = blockIdx.x;
    const int q = (b & 7) * 800 + (b >> 3);     // XCD-contiguous strips
    const int tid = threadIdx.x;
    const int lane = tid & 63, wave = tid >> 6;
    const int hw = lane >> 5, lh = lane & 31;
    const int slot = wave * 2 + hw;
    const int h = lh >> 2, chb = h * 32 + (lh & 3) * 8;
    __shared__ float s_un[24], s_vn[24], s_ok[24];
    __shared__ int s_list[24];
    __shared__ int s_n;
    __shared__ float s_cnt;
    __shared__ float s_ox[256], s_oy[256], s_wt[256];  // [pk=z*8+l*2+p][h]
    __shared__ float s_part[8][256];
    __shared__ __align__(16) u32 s_pre[256][8];        // [pt*8+h]: w00,w10,w01,w11,o00,o10,o01,o11
    const int jx = q % BEV, iy = q / BEV;
    const float wx = ((jx + 0.5f) / 80.f - 0.5f) * 40.96f;
    const float wy = ((iy + 0.5f) / 80.f - 0.5f) * 40.96f;
    if (tid < 24) {
        int v = tid >> 2, zz = tid & 3;
        float zr = zrefs[zz];
        const float* P = cam + v * 12;
        float u0 = P[0] * wx + P[1] * wy + P[2] * zr + P[3];
        float u1 = P[4] * wx + P[5] * wy + P[6] * zr + P[7];
        float dd = P[8] * wx + P[9] * wy + P[10] * zr + P[11];
        float dm = fmaxf(dd, 1e-5f);
        float un = u0 / dm / 800.f;
        float vn = u1 / dm / 480.f;
        bool ok = (dd > 1e-5f) && (un >= 0.f) && (un <= 1.f) && (vn >= 0.f) && (vn <= 1.f);
        s_un[tid] = un; s_vn[tid] = vn; s_ok[tid] = ok ? 1.f : 0.f;
    }
    {
        const u16* owq = ow + (size_t)q * 768;
        #pragma unroll
        for (int rep = 0; rep < 2; ++rep) {
            int flat = tid + rep * 256;
            int hh = flat >> 6, rem = flat & 63;
            int zz = rem >> 4, ll = (rem >> 2) & 3, pp = (rem >> 1) & 1, xy = rem & 1;
            int dst = (zz * 8 + ll * 2 + pp) * 8 + hh;
            float v = f16tof(owq[flat]);
            if (xy) s_oy[dst] = v; else s_ox[dst] = v;
        }
        int hh = tid >> 5, rem = tid & 31;
        s_wt[rem * 8 + hh] = f16tof(owq[512 + tid]);
    }
    __syncthreads();
    if (tid == 0) {
        int n = 0; float c = 0.f;
        for (int vz = 0; vz < 24; ++vz) {
            if (s_ok[vz] != 0.f) { s_list[n++] = vz; c += 1.f; }
        }
        s_n = n; s_cnt = fmaxf(c, 1.f);
    }
    __syncthreads();
    const int nchunk = (s_n + 3) >> 2;
    float a0 = 0.f, a1 = 0.f, a2 = 0.f, a3 = 0.f, a4 = 0.f, a5 = 0.f, a6 = 0.f, a7 = 0.f;
    const u16* valc = val + chb;
    for (int c = 0; c < nchunk; ++c) {
        // ---- phase A: one (point,head) tuple per thread ----
        {
            const int pi = tid >> 3, hh = tid & 7;
            const int li = c * 4 + (pi >> 3);
            const bool valid = li < s_n;
            const int vz = s_list[valid ? li : 0];
            const int v = vz >> 2, z = vz & 3;
            const int l = (pi >> 1) & 3, p = pi & 1;
            const int Hl  = (l == 0) ? 60  : (l == 1) ? 30   : (l == 2) ? 15   : 8;
            const int Wl  = (l == 0) ? 100 : (l == 1) ? 50   : (l == 2) ? 25   : 13;
            const int LSo = (l == 0) ? 0   : (l == 1) ? 6000 : (l == 2) ? 7500 : 7875;
            const int idx = (z * 8 + l * 2 + p) * 8 + hh;
            const float x = s_un[vz] * Wl - 0.5f + s_ox[idx];
            const float y = s_vn[vz] * Hl - 0.5f + s_oy[idx];
            const float wgt = valid ? s_wt[idx] : 0.f;
            const float xf = floorf(x), yf = floorf(y);
            const int x0 = (int)xf, y0 = (int)yf;
            const float fx = x - xf, fy = y - yf;
            const bool xi0 = (x0 >= 0) & (x0 < Wl);
            const bool xi1 = (x0 >= -1) & (x0 < Wl - 1);
            const bool yi0 = (y0 >= 0) & (y0 < Hl);
            const bool yi1 = (y0 >= -1) & (y0 < Hl - 1);
            const u32 xc0 = (u32)min(max(x0, 0), Wl - 1) << 8;
            const u32 xc1 = (u32)min(max(x0 + 1, 0), Wl - 1) << 8;
            const u32 base = (u32)(v * S_N + LSo) << 8;
            const u32 r0o = base + ((u32)(min(max(y0, 0), Hl - 1) * Wl) << 8);
            const u32 r1o = base + ((u32)(min(max(y0 + 1, 0), Hl - 1) * Wl) << 8);
            const float m00 = (xi0 & yi0) ? wgt : 0.f;
            const float m10 = (xi1 & yi0) ? wgt : 0.f;
            const float m01 = (xi0 & yi1) ? wgt : 0.f;
            const float m11 = (xi1 & yi1) ? wgt : 0.f;
            __half2 w00 = __float2half2_rn((1.f - fx) * (1.f - fy) * m00);
            __half2 w10 = __float2half2_rn(fx * (1.f - fy) * m10);
            __half2 w01 = __float2half2_rn((1.f - fx) * fy * m01);
            __half2 w11 = __float2half2_rn(fx * fy * m11);
            u32* pre = s_pre[tid];
            pre[0] = *(u32*)&w00; pre[1] = *(u32*)&w10;
            pre[2] = *(u32*)&w01; pre[3] = *(u32*)&w11;
            pre[4] = r0o + xc0;   pre[5] = r0o + xc1;
            pre[6] = r1o + xc0;   pre[7] = r1o + xc1;
        }
        __syncthreads();
        // ---- phase B: gathers only (4 points per slot) ----
        #pragma unroll
        for (int j = 0; j < 4; ++j) {
            const u32* pre = s_pre[(slot * 4 + j) * 8 + h];
            uint4 wv = *(const uint4*)(pre);
            uint4 ov = *(const uint4*)(pre + 4);
            uint4 u00 = *(const uint4*)(valc + ov.x);
            uint4 u10 = *(const uint4*)(valc + ov.y);
            uint4 u01 = *(const uint4*)(valc + ov.z);
            uint4 u11 = *(const uint4*)(valc + ov.w);
            __half2 w00 = *(__half2*)&wv.x, w10 = *(__half2*)&wv.y;
            __half2 w01 = *(__half2*)&wv.z, w11 = *(__half2*)&wv.w;
            __half2 h0 = __float2half2_rn(0.f), h1 = h0, h2 = h0, h3 = h0;
            {
                const __half2* hp = (const __half2*)&u00;
                h0 = __hfma2(w00, hp[0], h0); h1 = __hfma2(w00, hp[1], h1);
                h2 = __hfma2(w00, hp[2], h2); h3 = __hfma2(w00, hp[3], h3);
            }
            {
                const __half2* hp = (const __half2*)&u10;
                h0 = __hfma2(w10, hp[0], h0); h1 = __hfma2(w10, hp[1], h1);
                h2 = __hfma2(w10, hp[2], h2); h3 = __hfma2(w10, hp[3], h3);
            }
            {
                const __half2* hp = (const __half2*)&u01;
                h0 = __hfma2(w01, hp[0], h0); h1 = __hfma2(w01, hp[1], h1);
                h2 = __hfma2(w01, hp[2], h2); h3 = __hfma2(w01, hp[3], h3);
            }
            {
                const __half2* hp = (const __half2*)&u11;
                h0 = __hfma2(w11, hp[0], h0); h1 = __hfma2(w11, hp[1], h1);
                h2 = __hfma2(w11, hp[2], h2); h3 = __hfma2(w11, hp[3], h3);
            }
            float2 f0 = __half22float2(h0), f1 = __half22float2(h1);
            float2 f2 = __half22float2(h2), f3 = __half22float2(h3);
            a0 += f0.x; a1 += f0.y; a2 += f1.x; a3 += f1.y;
            a4 += f2.x; a5 += f2.y; a6 += f3.x; a7 += f3.y;
        }
        __syncthreads();
    }
    *(float4*)&s_part[slot][chb]     = make_float4(a0, a1, a2, a3);
    *(float4*)&s_part[slot][chb + 4] = make_float4(a4, a5, a6, a7);
    __syncthreads();
    float sum = 0.f;
    #pragma unroll
    for (int k = 0; k < 8; ++k) sum += s_part[k][tid];
    out[(size_t)q * 256 + tid] = sum / s_cnt;
}

extern "C" void kernel_launch(void* const* d_in, const int* in_sizes, int n_in,
                              void* d_out, int out_size, void* d_ws, size_t ws_size,
                              hipStream_t stream) {
    (void)in_sizes; (void)n_in; (void)out_size; (void)ws_size;
    const float* q      = (const float*)d_in[0];
    const float* hist   = (const float*)d_in[1];
    const float* fmaps  = (const float*)d_in[2];
    const float* Tm     = (const float*)d_in[3];
    const float* zrefs  = (const float*)d_in[4];
    const float* cam    = (const float*)d_in[5];
    const float* Woff_t = (const float*)d_in[7];
    const float* boff_t = (const float*)d_in[8];
    const float* Ww_t   = (const float*)d_in[9];
    const float* bw_t   = (const float*)d_in[10];
    const float* bo_t   = (const float*)d_in[12];
    const float* ln1g   = (const float*)d_in[13];
    const float* ln1b   = (const float*)d_in[14];
    const float* boff_s = (const float*)d_in[17];
    const float* bw_s   = (const float*)d_in[19];
    const float* bo_s   = (const float*)d_in[21];
    const float* ln2g   = (const float*)d_in[22];
    const float* ln2b   = (const float*)d_in[23];
    const float* b1     = (const float*)d_in[25];
    const float* b2     = (const float*)d_in[27];
    const float* ln3g   = (const float*)d_in[28];
    const float* ln3b   = (const float*)d_in[29];

    float* ws    = (float*)d_ws;
    float* r0    = ws;                   // sampled / out1 / out5            (1,638,400)
    float* r1    = ws + 1638400;         // out2                             (1,638,400)
    float* owt   = ws + 3276800;         // offt|wt fp32, 6400x128           (819,200)
    float* r4    = ws + 4096000;         // out_t / out3                     (1,638,400)
    u16*  r5u    = (u16*)(ws + 5734400); // off_s|w_s f16, 6400x768          (2,457,600 fl)
    float* of4   = ws + 8192000;         // out4                             (1,638,400)
    u16*  valbuf = (u16*)(ws + 9830400); // val_f16 12.25M u16 / hidden f16  (6,127,872 fl)
    u16*  vcur   = (u16*)(ws + 15958272);// 6400x256 f16                     (819,200 fl)
    u16*  vhist  = (u16*)(ws + 16777472);// 6400x256 f16                     (819,200 fl)
    u16*  wtab   = (u16*)(ws + 17596672);// f16 single tables, 753,664 u16
    float* st1   = ws + 17973504;        // LN1 stats: sum|sumsq (12,800)
    float* st2   = ws + 17986304;        // LN2 stats: sum|sumsq (12,800)
    float* bc    = ws + 18350336;        // 128

    u16* hidden = valbuf;  // reused after spatial
    u16* Wv_t_h = wtab + 0;
    u16* Wo_t_h = wtab + 65536;
    u16* Wv_s_h = wtab + 131072;
    u16* Comb_h = wtab + 196608;   // Woff_s|Ww_s (768,256)
    u16* Wo_s_h = wtab + 393216;
    u16* W1_h   = wtab + 458752;
    u16* W2_h   = wtab + 589824;
    u16* Wc_h   = wtab + 720896;

    dim3 blk(256);
    auto gc = [](int M, int N) { return dim3((unsigned)(N / 64), (unsigned)((M + 31) / 32)); };

    // 1) weight prep + zero LN-stat buffers
    wprep_k<<<dim3(285), blk, 0, stream>>>(
        (const float*)d_in[6], (const float*)d_in[11], (const float*)d_in[15],
        (const float*)d_in[16], (const float*)d_in[18], (const float*)d_in[20],
        (const float*)d_in[24], (const float*)d_in[26], wtab,
        Woff_t, Ww_t, boff_t, bw_t, bc, st1);
    // 2) fused head GEMMs (val, vcur, vhist, owt+softmax4)
    fused3_k<<<dim3(1998), blk, 0, stream>>>(
        fmaps, q, hist, Wv_s_h, Wv_t_h, Wc_h, bc,
        valbuf, vcur, vhist, owt);
    // 3) temporal sampling
    temporal_k<<<dim3(6400), blk, 0, stream>>>(vcur, vhist, owt, Tm, r4);
    // 4) out1 = out_t @ Wo_t + bo_t; accumulate LN1 stats of (out1+q) -> st1
    cgemm_k<0,0,0,0,1,0><<<gc(6400, 256), blk, 0, stream>>>(
        r4, Wo_t_h, bo_t, nullptr, q, st1, nullptr, nullptr, nullptr,
        r0, 6400, 256, 256);
    // 5) off_s|w_s = LN1(out1+q) @ Comb (LN in A-stage via st1; out2 -> r1)
    cgemm_k<0,0,1,1,0,1><<<gc(6400, 768), blk, 0, stream>>>(
        r0, Comb_h, boff_s, bw_s, q, st1, ln1g, ln1b, r1,
        r5u, 6400, 768, 256);
    // 6) spatial sampling
    spatial_k<<<dim3(6400), blk, 0, stream>>>(valbuf, r5u, cam, zrefs, r0);
    // 7) out3 = sampled @ Wo_s + bo_s; accumulate LN2 stats of (out3+out2) -> st2
    cgemm_k<0,0,0,0,1,0><<<gc(6400, 256), blk, 0, stream>>>(
        r0, Wo_s_h, bo_s, nullptr, r1, st2, nullptr, nullptr, nullptr,
        r4, 6400, 256, 256);
    // 8) hidden = relu(LN2(out3+out2) @ W1 + b1) -> f16 (LN in A-stage; out4 -> of4)
    cgemm_k<0,1,1,0,0,1><<<gc(6400, 512), blk, 0, stream>>>(
        r4, W1_h, b1, nullptr, r1, st2, ln2g, ln2b, of4,
        hidden, 6400, 512, 256);
    // 9) out5 = hidden @ W2 + b2
    cgemm_k<1,0,0,0,0,0><<<gc(6400, 256), blk, 0, stream>>>(
        hidden, W2_h, b2, nullptr, nullptr, nullptr, nullptr, nullptr, nullptr,
        r0, 6400, 256, 512);
    // 10) out = LN(out5 + out4)
    ln_k<<<dim3(6400), blk, 0, stream>>>(r0, of4, ln3g, ln3b, (float*)d_out);
}